// Round 17
// baseline (815.475 us; speedup 1.0000x reference)
//
#include <hip/hip_runtime.h>
#include <math.h>

#define N_PTS 8192
#define ICP_STEPS 21      // STEPLIM + 1 scan iterations
#define ICP_TOL 1e-4

#define NNB 512           // NN blocks (2 per CU)
#define QPB 16            // queries per block
#define QPWv 4            // queries per wave (wave owns them end-to-end)
#define CH 2048           // candidates per LDS chunk (32 KiB)
#define NCH 4             // 4 * 2048 = 8192

struct IcpCtl {
  double err;
  double Rc[9];     // cumulative rotation (row-major): pc = Rc*p1 + tc
  double tc[3];
  int done;
};

// ---------------------------------------------------------------------------
// prep: p2aug = (x,y,z,|b|^2) float4; ctl reset (runs every replay)
// ---------------------------------------------------------------------------
__global__ __launch_bounds__(256) void icp_prep(const float* __restrict__ p2,
                                                float4* __restrict__ p2aug,
                                                IcpCtl* __restrict__ ctl) {
  int t = blockIdx.x * 256 + threadIdx.x;   // grid covers exactly N_PTS
  float x = p2[3*t], y = p2[3*t+1], z = p2[3*t+2];
  p2aug[t] = make_float4(x, y, z, fmaf(x, x, fmaf(y, y, z*z)));
  if (t == 0) {
    ctl->err = 0.0; ctl->done = 0;
    #pragma unroll
    for (int i = 0; i < 9; ++i) ctl->Rc[i] = (i % 4 == 0) ? 1.0 : 0.0;
    ctl->tc[0] = ctl->tc[1] = ctl->tc[2] = 0.0;
  }
}

// ---------------------------------------------------------------------------
// NN + block pair-sums, ZERO atomics. 512 blocks x 256 thr (4 waves, 32 KB).
// Wave w owns queries qb+4w..qb+4w+3 entirely: lanes slice each LDS chunk
// 64-way, so the wave's butterfly argmin is FINAL for its queries -- no
// cross-block combine, no nn[] array. Output: 16 plain-stored pair sums.
// Packed u64 (ordered-dist, idx) keeps jnp.argmin tie semantics.
// d2' = |b|^2 - 2 a.b (|a|^2 dropped: argmin-invariant per query).
// ---------------------------------------------------------------------------
__global__ __launch_bounds__(256) void icp_nn(const float* __restrict__ p1,
                                              const float4* __restrict__ p2aug,
                                              const IcpCtl* __restrict__ ctl,
                                              double* __restrict__ part) {
  if (ctl->done) return;                     // uniform across grid
  __shared__ float4 cand[CH];                // 32 KiB
  __shared__ unsigned long long pkbuf[4][5]; // wave x query (+1 pad)
  __shared__ float4 qlds[QPB];
  __shared__ double pairbuf[QPB][17];        // +1 pad

  const int tid  = threadIdx.x;
  const int lane = tid & 63;
  const int w    = tid >> 6;                 // wave 0..3

  const double R0 = ctl->Rc[0], R1 = ctl->Rc[1], R2 = ctl->Rc[2];
  const double R3 = ctl->Rc[3], R4 = ctl->Rc[4], R5 = ctl->Rc[5];
  const double R6 = ctl->Rc[6], R7 = ctl->Rc[7], R8 = ctl->Rc[8];
  const double T0 = ctl->tc[0], T1 = ctl->tc[1], T2 = ctl->tc[2];

  // ---- wave w owns queries qb..qb+3 (uniform across its lanes) ----
  const int qb = blockIdx.x * QPB + (w << 2);
  float axv[QPWv], ayv[QPWv], azv[QPWv], best[QPWv];
  int bidx[QPWv];
  #pragma unroll
  for (int j = 0; j < QPWv; ++j) {
    const int q = qb + j;
    const double X = (double)p1[3*q], Y = (double)p1[3*q+1], Z = (double)p1[3*q+2];
    const float qx = (float)(R0*X + R1*Y + R2*Z + T0);  // fp32-rounded (ref pc)
    const float qy = (float)(R3*X + R4*Y + R5*Z + T1);
    const float qz = (float)(R6*X + R7*Y + R8*Z + T2);
    axv[j] = -2.f*qx; ayv[j] = -2.f*qy; azv[j] = -2.f*qz;
    best[j] = __builtin_inff(); bidx[j] = 0;
    if (lane == 0) qlds[(w << 2) + j] = make_float4(qx, qy, qz, 0.f);
  }

  // ---- scan all candidates: 4 chunks, reg-prefetch double-buffer ----
  float4 pf[8];
  #pragma unroll
  for (int k = 0; k < 8; ++k) pf[k] = p2aug[(k << 8) + tid];
  for (int cb = 0; cb < NCH; ++cb) {
    #pragma unroll
    for (int k = 0; k < 8; ++k) cand[(k << 8) + tid] = pf[k];
    __syncthreads();
    if (cb + 1 < NCH) {
      #pragma unroll
      for (int k = 0; k < 8; ++k)
        pf[k] = p2aug[((cb + 1) << 11) + (k << 8) + tid];
    }
    const int cbase = cb << 11;
    #pragma unroll 8
    for (int kk = 0; kk < 32; ++kk) {
      const int cidx = cbase + (kk << 6) + lane;
      float4 c = cand[(kk << 6) + lane];     // ds_read_b128, conflict-free
      #pragma unroll
      for (int j = 0; j < QPWv; ++j) {
        float d = fmaf(axv[j], c.x, fmaf(ayv[j], c.y, fmaf(azv[j], c.z, c.w)));
        if (d < best[j]) { best[j] = d; bidx[j] = cidx; }
      }
    }
    __syncthreads();
  }

  // ---- wave-local final argmin: packed u64 butterfly ----
  unsigned long long pk[QPWv];
  #pragma unroll
  for (int j = 0; j < QPWv; ++j) {
    unsigned u = __float_as_uint(best[j]);
    u ^= (unsigned)((int)u >> 31) | 0x80000000u;   // monotone float->uint
    pk[j] = ((unsigned long long)u << 32) | (unsigned)bidx[j];
  }
  #pragma unroll
  for (int j = 0; j < QPWv; ++j) {
    #pragma unroll
    for (int o = 1; o < 64; o <<= 1) {
      unsigned long long other = __shfl_xor(pk[j], o, 64);
      pk[j] = (other < pk[j]) ? other : pk[j];
    }
  }
  if (lane == 0) {
    #pragma unroll
    for (int j = 0; j < QPWv; ++j) pkbuf[w][j] = pk[j];
  }
  __syncthreads();

  // ---- pair sums: tid<16 handles one query (LDS-indexed, no reg arrays) ----
  if (tid < QPB) {
    const unsigned long long m = pkbuf[tid >> 2][tid & 3];
    const unsigned idx = (unsigned)(m & 0xffffffffull);
    const float4 q4 = qlds[tid];
    const float4 b4 = p2aug[idx];            // L2-resident gather
    const double ax = q4.x, ay = q4.y, az = q4.z;
    const double bx = b4.x, by = b4.y, bz = b4.z;
    const double d2 = (ax*ax + ay*ay + az*az) + (bx*bx + by*by + bz*bz)
                    - 2.0*(ax*bx + ay*by + az*bz);
    pairbuf[tid][0]  = sqrt(fmax(d2, 1e-12));
    pairbuf[tid][1]  = ax;    pairbuf[tid][2]  = ay;    pairbuf[tid][3]  = az;
    pairbuf[tid][4]  = bx;    pairbuf[tid][5]  = by;    pairbuf[tid][6]  = bz;
    pairbuf[tid][7]  = ax*bx; pairbuf[tid][8]  = ax*by; pairbuf[tid][9]  = ax*bz;
    pairbuf[tid][10] = ay*bx; pairbuf[tid][11] = ay*by; pairbuf[tid][12] = ay*bz;
    pairbuf[tid][13] = az*bx; pairbuf[tid][14] = az*by; pairbuf[tid][15] = az*bz;
  }
  __syncthreads();

  // ---- 16 column sums -> plain stores (R9-proven-fast handoff) ----
  if (tid < 16) {
    double s = 0.0;
    #pragma unroll
    for (int i = 0; i < QPB; ++i) s += pairbuf[i][tid];
    part[(blockIdx.x << 4) + tid] = s;
  }
}

// ---------------------------------------------------------------------------
// Register-only 3x3 Kabsch from raw sums (no runtime-indexed reg arrays).
// s[0]=sum dmin, s[1..3]=sum src, s[4..6]=sum dst, s[7..15]=sum src_i*dst_j.
// R = V diag(1,1,detV) U~^T (right-handed U~) == reference's sign-fixed SVD.
// ---------------------------------------------------------------------------
__device__ __forceinline__ void kabsch_solve(const double* s, double* R, double* T) {
  const double n = (double)N_PTS;
  const double c1x = s[1]/n, c1y = s[2]/n, c1z = s[3]/n;
  const double c2x = s[4]/n, c2y = s[5]/n, c2z = s[6]/n;
  const double h00 = s[7]  - n*c1x*c2x, h01 = s[8]  - n*c1x*c2y, h02 = s[9]  - n*c1x*c2z;
  const double h10 = s[10] - n*c1y*c2x, h11 = s[11] - n*c1y*c2y, h12 = s[12] - n*c1y*c2z;
  const double h20 = s[13] - n*c1z*c2x, h21 = s[14] - n*c1z*c2y, h22 = s[15] - n*c1z*c2z;

  double a00 = h00*h00 + h10*h10 + h20*h20;
  double a01 = h00*h01 + h10*h11 + h20*h21;
  double a02 = h00*h02 + h10*h12 + h20*h22;
  double a11 = h01*h01 + h11*h11 + h21*h21;
  double a12 = h01*h02 + h11*h12 + h21*h22;
  double a22 = h02*h02 + h12*h12 + h22*h22;

  double v00=1.0, v01=0.0, v02=0.0;
  double v10=0.0, v11=1.0, v12=0.0;
  double v20=0.0, v21=0.0, v22=1.0;

#define ROT3(app, aqq, apq, arp, arq, vpa, vqa, vpb, vqb, vpc, vqc)              \
  {                                                                              \
    double apq_ = apq;                                                           \
    if (fabs(apq_) > 1e-300) {                                                   \
      double tau = (aqq - app) / (2.0 * apq_);                                   \
      double tt  = (tau >= 0.0 ? 1.0 : -1.0) / (fabs(tau) + sqrt(1.0 + tau*tau));\
      double c_  = 1.0 / sqrt(1.0 + tt*tt), sn = tt * c_;                        \
      app -= tt * apq_;  aqq += tt * apq_;  apq = 0.0;                           \
      double t1 = arp, t2 = arq;                                                 \
      arp = c_*t1 - sn*t2;  arq = sn*t1 + c_*t2;                                 \
      t1 = vpa; t2 = vqa; vpa = c_*t1 - sn*t2; vqa = sn*t1 + c_*t2;              \
      t1 = vpb; t2 = vqb; vpb = c_*t1 - sn*t2; vqb = sn*t1 + c_*t2;              \
      t1 = vpc; t2 = vqc; vpc = c_*t1 - sn*t2; vqc = sn*t1 + c_*t2;              \
    }                                                                            \
  }

  #pragma unroll
  for (int sweep = 0; sweep < 6; ++sweep) {
    ROT3(a00, a11, a01, a02, a12, v00, v01, v10, v11, v20, v21);  // (0,1)
    ROT3(a00, a22, a02, a01, a12, v00, v02, v10, v12, v20, v22);  // (0,2)
    ROT3(a11, a22, a12, a01, a02, v01, v02, v11, v12, v21, v22);  // (1,2)
  }
#undef ROT3

  double l0 = a00, l1 = a11, l2 = a22;
  double e0x=v00, e0y=v10, e0z=v20;
  double e1x=v01, e1y=v11, e1z=v21;
  double e2x=v02, e2y=v12, e2z=v22;
#define CSWAP(la, lb, xa, ya, za, xb, yb, zb)                                    \
  if (lb > la) { double t_;                                                      \
    t_ = la; la = lb; lb = t_;  t_ = xa; xa = xb; xb = t_;                       \
    t_ = ya; ya = yb; yb = t_;  t_ = za; za = zb; zb = t_; }
  CSWAP(l0, l1, e0x, e0y, e0z, e1x, e1y, e1z);
  CSWAP(l0, l2, e0x, e0y, e0z, e2x, e2y, e2z);
  CSWAP(l1, l2, e1x, e1y, e1z, e2x, e2y, e2z);
#undef CSWAP

  double detV = e0x*(e1y*e2z - e1z*e2y) - e0y*(e1x*e2z - e1z*e2x)
              + e0z*(e1x*e2y - e1y*e2x);
  const double dsg = (detV >= 0.0) ? 1.0 : -1.0;

  double u0x = h00*e0x + h01*e0y + h02*e0z;
  double u0y = h10*e0x + h11*e0y + h12*e0z;
  double u0z = h20*e0x + h21*e0y + h22*e0z;
  double n0 = sqrt(u0x*u0x + u0y*u0y + u0z*u0z);
  if (!(n0 > 1e-150)) {
    R[0]=1.0; R[1]=0.0; R[2]=0.0; R[3]=0.0; R[4]=1.0; R[5]=0.0;
    R[6]=0.0; R[7]=0.0; R[8]=1.0;
    T[0]=c2x-c1x; T[1]=c2y-c1y; T[2]=c2z-c1z;
    return;
  }
  u0x /= n0; u0y /= n0; u0z /= n0;
  double u1x = h00*e1x + h01*e1y + h02*e1z;
  double u1y = h10*e1x + h11*e1y + h12*e1z;
  double u1z = h20*e1x + h21*e1y + h22*e1z;
  const double d10 = u1x*u0x + u1y*u0y + u1z*u0z;
  u1x -= d10*u0x; u1y -= d10*u0y; u1z -= d10*u0z;
  double n1 = sqrt(u1x*u1x + u1y*u1y + u1z*u1z);
  if (!(n1 > 1e-150)) {
    R[0]=1.0; R[1]=0.0; R[2]=0.0; R[3]=0.0; R[4]=1.0; R[5]=0.0;
    R[6]=0.0; R[7]=0.0; R[8]=1.0;
    T[0]=c2x-c1x; T[1]=c2y-c1y; T[2]=c2z-c1z;
    return;
  }
  u1x /= n1; u1y /= n1; u1z /= n1;
  const double u2x = u0y*u1z - u0z*u1y;
  const double u2y = u0z*u1x - u0x*u1z;
  const double u2z = u0x*u1y - u0y*u1x;

  R[0] = e0x*u0x + e1x*u1x + dsg*e2x*u2x;
  R[1] = e0x*u0y + e1x*u1y + dsg*e2x*u2y;
  R[2] = e0x*u0z + e1x*u1z + dsg*e2x*u2z;
  R[3] = e0y*u0x + e1y*u1x + dsg*e2y*u2x;
  R[4] = e0y*u0y + e1y*u1y + dsg*e2y*u2y;
  R[5] = e0y*u0z + e1y*u1z + dsg*e2y*u2z;
  R[6] = e0z*u0x + e1z*u1x + dsg*e2z*u2x;
  R[7] = e0z*u0y + e1z*u1y + dsg*e2z*u2y;
  R[8] = e0z*u0z + e1z*u1z + dsg*e2z*u2z;
  T[0] = c2x - (R[0]*c1x + R[1]*c1y + R[2]*c1z);
  T[1] = c2y - (R[3]*c1x + R[4]*c1y + R[5]*c1z);
  T[2] = c2z - (R[6]*c1x + R[7]*c1y + R[8]*c1z);
}

// ---------------------------------------------------------------------------
// solve (1 block x 512): reduce 512x16 plain-stored partial rows (1 row per
// thread; R9-proven handoff), register Kabsch on tid0, compose, done-logic,
// write out + ctl. Kernel-boundary coherence.
// ---------------------------------------------------------------------------
__global__ __launch_bounds__(512) void icp_solve(IcpCtl* __restrict__ ctl,
                                                 const double* __restrict__ part,
                                                 float* __restrict__ out) {
  if (ctl->done) return;
  __shared__ double lds[8 * 16];
  __shared__ double tot[16];
  const int tid  = threadIdx.x;
  const int lane = tid & 63;
  const int w    = tid >> 6;                 // 8 waves

  double v[16];
  const double* row = part + (tid << 4);
  #pragma unroll
  for (int c = 0; c < 16; ++c) v[c] = row[c];
  #pragma unroll
  for (int q = 0; q < 16; ++q) {
    double x = v[q];
    for (int o = 32; o > 0; o >>= 1) x += __shfl_down(x, o, 64);
    if (lane == 0) lds[w*16 + q] = x;
  }
  __syncthreads();
  if (tid < 16) {
    double s = 0.0;
    #pragma unroll
    for (int r = 0; r < 8; ++r) s += lds[r*16 + tid];
    tot[tid] = s;
  }
  __syncthreads();

  if (tid == 0) {
    double sm[16];
    #pragma unroll
    for (int i = 0; i < 16; ++i) sm[i] = tot[i];
    double R[9], T[3];
    kabsch_solve(sm, R, T);
    // compose: pc_new = R*(Rc*p1 + tc) + T = (R*Rc)*p1 + (R*tc + T)
    double Rc[9], tc[3], Rn[9], tn[3];
    #pragma unroll
    for (int i = 0; i < 9; ++i) Rc[i] = ctl->Rc[i];
    #pragma unroll
    for (int i = 0; i < 3; ++i) tc[i] = ctl->tc[i];
    #pragma unroll
    for (int i = 0; i < 3; ++i) {
      #pragma unroll
      for (int j = 0; j < 3; ++j)
        Rn[3*i+j] = R[3*i+0]*Rc[0+j] + R[3*i+1]*Rc[3+j] + R[3*i+2]*Rc[6+j];
      tn[i] = R[3*i+0]*tc[0] + R[3*i+1]*tc[1] + R[3*i+2]*tc[2] + T[i];
    }
    #pragma unroll
    for (int i = 0; i < 9; ++i) ctl->Rc[i] = Rn[i];
    #pragma unroll
    for (int i = 0; i < 3; ++i) ctl->tc[i] = tn[i];
    const double errnew = sm[0];            // B == 1
    ctl->done = (fabs(ctl->err - errnew) < ICP_TOL) ? 1 : 0;
    ctl->err  = errnew;
    // out = [Rc | tc] 3x4 (kabsch(p1, Rc*p1+tc) == (Rc,tc) exactly).
    #pragma unroll
    for (int i = 0; i < 3; ++i) {
      out[4*i + 0] = (float)Rn[3*i + 0];
      out[4*i + 1] = (float)Rn[3*i + 1];
      out[4*i + 2] = (float)Rn[3*i + 2];
      out[4*i + 3] = (float)tn[i];
    }
  }
}

// ---------------------------------------------------------------------------
extern "C" void kernel_launch(void* const* d_in, const int* in_sizes, int n_in,
                              void* d_out, int out_size, void* d_ws, size_t ws_size,
                              hipStream_t stream) {
  const float* p1 = (const float*)d_in[0];
  const float* p2 = (const float*)d_in[1];
  float* out = (float*)d_out;

  char* ws = (char*)d_ws;
  float4* p2aug = (float4*)ws;                   // 128 KiB
  IcpCtl* ctl   = (IcpCtl*)(ws + 128*1024);      // ~112 B
  double* part  = (double*)(ws + 132*1024);      // 64 KiB (512 x 16 f64)

  icp_prep<<<N_PTS/256, 256, 0, stream>>>(p2, p2aug, ctl);
  for (int it = 0; it < ICP_STEPS; ++it) {
    icp_nn<<<NNB, 256, 0, stream>>>(p1, p2aug, ctl, part);
    icp_solve<<<1, 512, 0, stream>>>(ctl, part, out);
  }
}

// Round 18
// 803.154 us; speedup vs baseline: 1.0153x; 1.0153x over previous
//
#include <hip/hip_runtime.h>
#include <math.h>

#define N_PTS 8192
#define ICP_STEPS 21      // STEPLIM + 1 scan iterations
#define ICP_TOL 1e-4

#define NNB 256           // blocks; block owns 32 queries (4 waves x 8)
#define QPWv 8            // queries per wave (wave owns them end-to-end)
#define QPB 32            // queries per block
#define CH 2048           // candidates per LDS chunk (32 KiB)
#define NCH 4             // 4 * 2048 = 8192

// state_j in slot j%2; part of step k in slot k%2 (R11-proven layout)
struct IcpSt {
  double Rc[9];     // cumulative rotation (row-major): pc = Rc*p1 + tc
  double tc[3];
  double err;
  int done;
};

// ---------------------------------------------------------------------------
// prep: p2aug = (x,y,z,|b|^2) float4; st0 = identity state
// ---------------------------------------------------------------------------
__global__ __launch_bounds__(256) void icp_prep(const float* __restrict__ p2,
                                                float4* __restrict__ p2aug,
                                                IcpSt* __restrict__ st0) {
  int t = blockIdx.x * 256 + threadIdx.x;   // grid covers exactly N_PTS
  float x = p2[3*t], y = p2[3*t+1], z = p2[3*t+2];
  p2aug[t] = make_float4(x, y, z, fmaf(x, x, fmaf(y, y, z*z)));
  if (t == 0) {
    #pragma unroll
    for (int i = 0; i < 9; ++i) st0->Rc[i] = (i % 4 == 0) ? 1.0 : 0.0;
    st0->tc[0] = st0->tc[1] = st0->tc[2] = 0.0;
    st0->err = 0.0; st0->done = 0;
  }
}

// ---------------------------------------------------------------------------
// Register-only 3x3 Kabsch from raw sums (no runtime-indexed reg arrays).
// s[0]=sum dmin, s[1..3]=sum src, s[4..6]=sum dst, s[7..15]=sum src_i*dst_j.
// R = V diag(1,1,detV) U~^T (right-handed U~) == reference's sign-fixed SVD.
// ---------------------------------------------------------------------------
__device__ __forceinline__ void kabsch_solve(const double* s, double* R, double* T) {
  const double n = (double)N_PTS;
  const double c1x = s[1]/n, c1y = s[2]/n, c1z = s[3]/n;
  const double c2x = s[4]/n, c2y = s[5]/n, c2z = s[6]/n;
  const double h00 = s[7]  - n*c1x*c2x, h01 = s[8]  - n*c1x*c2y, h02 = s[9]  - n*c1x*c2z;
  const double h10 = s[10] - n*c1y*c2x, h11 = s[11] - n*c1y*c2y, h12 = s[12] - n*c1y*c2z;
  const double h20 = s[13] - n*c1z*c2x, h21 = s[14] - n*c1z*c2y, h22 = s[15] - n*c1z*c2z;

  double a00 = h00*h00 + h10*h10 + h20*h20;
  double a01 = h00*h01 + h10*h11 + h20*h21;
  double a02 = h00*h02 + h10*h12 + h20*h22;
  double a11 = h01*h01 + h11*h11 + h21*h21;
  double a12 = h01*h02 + h11*h12 + h21*h22;
  double a22 = h02*h02 + h12*h12 + h22*h22;

  double v00=1.0, v01=0.0, v02=0.0;
  double v10=0.0, v11=1.0, v12=0.0;
  double v20=0.0, v21=0.0, v22=1.0;

#define ROT3(app, aqq, apq, arp, arq, vpa, vqa, vpb, vqb, vpc, vqc)              \
  {                                                                              \
    double apq_ = apq;                                                           \
    if (fabs(apq_) > 1e-300) {                                                   \
      double tau = (aqq - app) / (2.0 * apq_);                                   \
      double tt  = (tau >= 0.0 ? 1.0 : -1.0) / (fabs(tau) + sqrt(1.0 + tau*tau));\
      double c_  = 1.0 / sqrt(1.0 + tt*tt), sn = tt * c_;                        \
      app -= tt * apq_;  aqq += tt * apq_;  apq = 0.0;                           \
      double t1 = arp, t2 = arq;                                                 \
      arp = c_*t1 - sn*t2;  arq = sn*t1 + c_*t2;                                 \
      t1 = vpa; t2 = vqa; vpa = c_*t1 - sn*t2; vqa = sn*t1 + c_*t2;              \
      t1 = vpb; t2 = vqb; vpb = c_*t1 - sn*t2; vqb = sn*t1 + c_*t2;              \
      t1 = vpc; t2 = vqc; vpc = c_*t1 - sn*t2; vqc = sn*t1 + c_*t2;              \
    }                                                                            \
  }

  #pragma unroll
  for (int sweep = 0; sweep < 6; ++sweep) {
    ROT3(a00, a11, a01, a02, a12, v00, v01, v10, v11, v20, v21);  // (0,1)
    ROT3(a00, a22, a02, a01, a12, v00, v02, v10, v12, v20, v22);  // (0,2)
    ROT3(a11, a22, a12, a01, a02, v01, v02, v11, v12, v21, v22);  // (1,2)
  }
#undef ROT3

  double l0 = a00, l1 = a11, l2 = a22;
  double e0x=v00, e0y=v10, e0z=v20;
  double e1x=v01, e1y=v11, e1z=v21;
  double e2x=v02, e2y=v12, e2z=v22;
#define CSWAP(la, lb, xa, ya, za, xb, yb, zb)                                    \
  if (lb > la) { double t_;                                                      \
    t_ = la; la = lb; lb = t_;  t_ = xa; xa = xb; xb = t_;                       \
    t_ = ya; ya = yb; yb = t_;  t_ = za; za = zb; zb = t_; }
  CSWAP(l0, l1, e0x, e0y, e0z, e1x, e1y, e1z);
  CSWAP(l0, l2, e0x, e0y, e0z, e2x, e2y, e2z);
  CSWAP(l1, l2, e1x, e1y, e1z, e2x, e2y, e2z);
#undef CSWAP

  double detV = e0x*(e1y*e2z - e1z*e2y) - e0y*(e1x*e2z - e1z*e2x)
              + e0z*(e1x*e2y - e1y*e2x);
  const double dsg = (detV >= 0.0) ? 1.0 : -1.0;

  double u0x = h00*e0x + h01*e0y + h02*e0z;
  double u0y = h10*e0x + h11*e0y + h12*e0z;
  double u0z = h20*e0x + h21*e0y + h22*e0z;
  double n0 = sqrt(u0x*u0x + u0y*u0y + u0z*u0z);
  if (!(n0 > 1e-150)) {
    R[0]=1.0; R[1]=0.0; R[2]=0.0; R[3]=0.0; R[4]=1.0; R[5]=0.0;
    R[6]=0.0; R[7]=0.0; R[8]=1.0;
    T[0]=c2x-c1x; T[1]=c2y-c1y; T[2]=c2z-c1z;
    return;
  }
  u0x /= n0; u0y /= n0; u0z /= n0;
  double u1x = h00*e1x + h01*e1y + h02*e1z;
  double u1y = h10*e1x + h11*e1y + h12*e1z;
  double u1z = h20*e1x + h21*e1y + h22*e1z;
  const double d10 = u1x*u0x + u1y*u0y + u1z*u0z;
  u1x -= d10*u0x; u1y -= d10*u0y; u1z -= d10*u0z;
  double n1 = sqrt(u1x*u1x + u1y*u1y + u1z*u1z);
  if (!(n1 > 1e-150)) {
    R[0]=1.0; R[1]=0.0; R[2]=0.0; R[3]=0.0; R[4]=1.0; R[5]=0.0;
    R[6]=0.0; R[7]=0.0; R[8]=1.0;
    T[0]=c2x-c1x; T[1]=c2y-c1y; T[2]=c2z-c1z;
    return;
  }
  u1x /= n1; u1y /= n1; u1z /= n1;
  const double u2x = u0y*u1z - u0z*u1y;
  const double u2y = u0z*u1x - u0x*u1z;
  const double u2z = u0x*u1y - u0y*u1x;

  R[0] = e0x*u0x + e1x*u1x + dsg*e2x*u2x;
  R[1] = e0x*u0y + e1x*u1y + dsg*e2x*u2y;
  R[2] = e0x*u0z + e1x*u1z + dsg*e2x*u2z;
  R[3] = e0y*u0x + e1y*u1x + dsg*e2y*u2x;
  R[4] = e0y*u0y + e1y*u1y + dsg*e2y*u2y;
  R[5] = e0y*u0z + e1y*u1z + dsg*e2y*u2z;
  R[6] = e0z*u0x + e1z*u1x + dsg*e2z*u2x;
  R[7] = e0z*u0y + e1z*u1y + dsg*e2z*u2y;
  R[8] = e0z*u0z + e1z*u1z + dsg*e2z*u2z;
  T[0] = c2x - (R[0]*c1x + R[1]*c1y + R[2]*c1z);
  T[1] = c2y - (R[3]*c1x + R[4]*c1y + R[5]*c1z);
  T[2] = c2z - (R[6]*c1x + R[7]*c1y + R[8]*c1z);
}

// solve step: sums s[16] + stIn state -> composed Rn/tn, errnew, done flag
__device__ __forceinline__ void solve_compose(const double* s, const IcpSt* stIn,
                                              double* Rn, double* tn,
                                              double* errnew, int* dn) {
  double R[9], T[3];
  kabsch_solve(s, R, T);
  double Rc[9], tc[3];
  #pragma unroll
  for (int i = 0; i < 9; ++i) Rc[i] = stIn->Rc[i];
  #pragma unroll
  for (int i = 0; i < 3; ++i) tc[i] = stIn->tc[i];
  // pc_new = R*(Rc*p1 + tc) + T = (R*Rc)*p1 + (R*tc + T)
  #pragma unroll
  for (int i = 0; i < 3; ++i) {
    #pragma unroll
    for (int j = 0; j < 3; ++j)
      Rn[3*i+j] = R[3*i+0]*Rc[0+j] + R[3*i+1]*Rc[3+j] + R[3*i+2]*Rc[6+j];
    tn[i] = R[3*i+0]*tc[0] + R[3*i+1]*tc[1] + R[3*i+2]*tc[2] + T[i];
  }
  *errnew = s[0];                           // B == 1
  *dn = (fabs(stIn->err - *errnew) < ICP_TOL) ? 1 : 0;
}

// ---------------------------------------------------------------------------
// Fused dispatch k: [every block redundantly solves step k-1 from partIn
// (256 rows read in PARALLEL across 256 blocks -> +6us, R11-proven) ->
// state_k + done-check] then [small-block NN for step k -> partOut].
// 256 thr / 37 KB LDS blocks (fast launch, R17-proven ~10us NN).
// No atomics anywhere. Double-buffered st/part; benign identical stOut
// writes (R11-proven, absmax 0.0).
// ---------------------------------------------------------------------------
__global__ __launch_bounds__(256) void icp_iter(const float* __restrict__ p1,
                                                const float4* __restrict__ p2aug,
                                                const IcpSt* __restrict__ stIn,
                                                IcpSt* __restrict__ stOut,
                                                const double* __restrict__ partIn,
                                                double* __restrict__ partOut,
                                                const int k) {
  __shared__ float4 cand[CH];                // 32 KiB
  __shared__ double redbuf[64];              // 4 waves x 16 (solve phase)
  __shared__ double RT[12];
  __shared__ int sdone;
  __shared__ unsigned long long pkbuf[4][9]; // wave x 8 queries (+1 pad)
  __shared__ float4 qlds[QPB];
  __shared__ double pairbuf[QPB][17];        // +1 pad

  const int tid  = threadIdx.x;
  const int lane = tid & 63;
  const int w    = tid >> 6;                 // wave 0..3

  // ---- frozen? propagate state and stop (uniform; R11-proven chain) ----
  if (stIn->done) {
    if (blockIdx.x == 0 && tid == 0) {
      #pragma unroll
      for (int i = 0; i < 9; ++i) stOut->Rc[i] = stIn->Rc[i];
      #pragma unroll
      for (int i = 0; i < 3; ++i) stOut->tc[i] = stIn->tc[i];
      stOut->err = stIn->err; stOut->done = 1;
    }
    return;
  }

  // ---- issue chunk-0 staging loads early (overlap with solve phase) ----
  float4 pf[8];
  #pragma unroll
  for (int kk = 0; kk < 8; ++kk) pf[kk] = p2aug[(kk << 8) + tid];

  // ---- solve phase for step k-1 (every block, redundant, parallel) ----
  double R0, R1, R2, R3, R4, R5, R6, R7, R8, T0, T1, T2;
  if (k > 0) {
    double vv[16];
    {
      const double* row = partIn + (tid << 4);   // 1 row per thread (2 lines)
      #pragma unroll
      for (int c = 0; c < 16; ++c) vv[c] = row[c];
    }
    #pragma unroll
    for (int q = 0; q < 16; ++q) {
      double x = vv[q];
      for (int o = 32; o > 0; o >>= 1) x += __shfl_down(x, o, 64);
      if (lane == 0) redbuf[w*16 + q] = x;
    }
    __syncthreads();
    if (tid == 0) {
      double sm[16];
      #pragma unroll
      for (int i = 0; i < 16; ++i)
        sm[i] = redbuf[i] + redbuf[16+i] + redbuf[32+i] + redbuf[48+i];
      double Rn[9], tn[3], errnew; int dn;
      solve_compose(sm, stIn, Rn, tn, &errnew, &dn);
      // stOut: 256 blocks write bitwise-identical values (benign race)
      #pragma unroll
      for (int i = 0; i < 9; ++i) stOut->Rc[i] = Rn[i];
      #pragma unroll
      for (int i = 0; i < 3; ++i) stOut->tc[i] = tn[i];
      stOut->err = errnew; stOut->done = dn;
      #pragma unroll
      for (int i = 0; i < 9; ++i) RT[i] = Rn[i];
      RT[9] = tn[0]; RT[10] = tn[1]; RT[11] = tn[2];
      sdone = dn;
    }
    __syncthreads();
    if (sdone) return;                      // step k frozen (uniform)
    R0 = RT[0]; R1 = RT[1]; R2 = RT[2];
    R3 = RT[3]; R4 = RT[4]; R5 = RT[5];
    R6 = RT[6]; R7 = RT[7]; R8 = RT[8];
    T0 = RT[9]; T1 = RT[10]; T2 = RT[11];
  } else {
    R0 = stIn->Rc[0]; R1 = stIn->Rc[1]; R2 = stIn->Rc[2];
    R3 = stIn->Rc[3]; R4 = stIn->Rc[4]; R5 = stIn->Rc[5];
    R6 = stIn->Rc[6]; R7 = stIn->Rc[7]; R8 = stIn->Rc[8];
    T0 = stIn->tc[0]; T1 = stIn->tc[1]; T2 = stIn->tc[2];
  }

  // ---- wave w owns queries qb..qb+7 end-to-end (uniform across lanes) ----
  const int qb = (blockIdx.x << 5) + (w << 3);
  float axv[QPWv], ayv[QPWv], azv[QPWv], best[QPWv];
  int bidx[QPWv];
  #pragma unroll
  for (int j = 0; j < QPWv; ++j) {
    const int q = qb + j;
    const double X = (double)p1[3*q], Y = (double)p1[3*q+1], Z = (double)p1[3*q+2];
    const float qx = (float)(R0*X + R1*Y + R2*Z + T0);  // fp32-rounded (ref pc)
    const float qy = (float)(R3*X + R4*Y + R5*Z + T1);
    const float qz = (float)(R6*X + R7*Y + R8*Z + T2);
    axv[j] = -2.f*qx; ayv[j] = -2.f*qy; azv[j] = -2.f*qz;
    best[j] = __builtin_inff(); bidx[j] = 0;
    if (lane == 0) qlds[(w << 3) + j] = make_float4(qx, qy, qz, 0.f);
  }

  // ---- scan all candidates: 4 chunks, reg-prefetch double-buffer ----
  for (int cb = 0; cb < NCH; ++cb) {
    #pragma unroll
    for (int kk = 0; kk < 8; ++kk) cand[(kk << 8) + tid] = pf[kk];
    __syncthreads();
    if (cb + 1 < NCH) {
      #pragma unroll
      for (int kk = 0; kk < 8; ++kk)
        pf[kk] = p2aug[((cb + 1) << 11) + (kk << 8) + tid];
    }
    const int cbase = cb << 11;
    #pragma unroll 4
    for (int kk = 0; kk < 32; ++kk) {
      const int cidx = cbase + (kk << 6) + lane;
      float4 c = cand[(kk << 6) + lane];     // ds_read_b128, conflict-free
      #pragma unroll
      for (int j = 0; j < QPWv; ++j) {
        float d = fmaf(axv[j], c.x, fmaf(ayv[j], c.y, fmaf(azv[j], c.z, c.w)));
        if (d < best[j]) { best[j] = d; bidx[j] = cidx; }
      }
    }
    __syncthreads();
  }

  // ---- wave-local FINAL argmin: packed u64 butterfly (jnp tie semantics) --
  unsigned long long pk[QPWv];
  #pragma unroll
  for (int j = 0; j < QPWv; ++j) {
    unsigned u = __float_as_uint(best[j]);
    u ^= (unsigned)((int)u >> 31) | 0x80000000u;   // monotone float->uint
    pk[j] = ((unsigned long long)u << 32) | (unsigned)bidx[j];
  }
  #pragma unroll
  for (int j = 0; j < QPWv; ++j) {
    #pragma unroll
    for (int o = 1; o < 64; o <<= 1) {
      unsigned long long other = __shfl_xor(pk[j], o, 64);
      pk[j] = (other < pk[j]) ? other : pk[j];
    }
  }
  if (lane == 0) {
    #pragma unroll
    for (int j = 0; j < QPWv; ++j) pkbuf[w][j] = pk[j];
  }
  __syncthreads();

  // ---- pair sums: tid<32 handles one query (LDS-indexed, static) ----
  if (tid < QPB) {
    const unsigned long long m = pkbuf[tid >> 3][tid & 7];
    const unsigned idx = (unsigned)(m & 0xffffffffull);
    const float4 q4 = qlds[tid];
    const float4 b4 = p2aug[idx];            // L2-resident gather
    const double ax = q4.x, ay = q4.y, az = q4.z;
    const double bx = b4.x, by = b4.y, bz = b4.z;
    const double d2 = (ax*ax + ay*ay + az*az) + (bx*bx + by*by + bz*bz)
                    - 2.0*(ax*bx + ay*by + az*bz);
    pairbuf[tid][0]  = sqrt(fmax(d2, 1e-12));
    pairbuf[tid][1]  = ax;    pairbuf[tid][2]  = ay;    pairbuf[tid][3]  = az;
    pairbuf[tid][4]  = bx;    pairbuf[tid][5]  = by;    pairbuf[tid][6]  = bz;
    pairbuf[tid][7]  = ax*bx; pairbuf[tid][8]  = ax*by; pairbuf[tid][9]  = ax*bz;
    pairbuf[tid][10] = ay*bx; pairbuf[tid][11] = ay*by; pairbuf[tid][12] = ay*bz;
    pairbuf[tid][13] = az*bx; pairbuf[tid][14] = az*by; pairbuf[tid][15] = az*bz;
  }
  __syncthreads();

  // ---- 16 column sums -> plain stores to this block's part row ----
  if (tid < 16) {
    double s = 0.0;
    #pragma unroll
    for (int i = 0; i < QPB; ++i) s += pairbuf[i][tid];
    partOut[(blockIdx.x << 4) + tid] = s;
  }
}

// ---------------------------------------------------------------------------
// final (1 block x 256): solve step 20 (if still active) and emit [R|t] 3x4.
// One-time single-CU read of 512 lines (~20-40us once) -- acceptable.
// ---------------------------------------------------------------------------
__global__ __launch_bounds__(256) void icp_final(const IcpSt* __restrict__ stIn,
                                                 const double* __restrict__ partIn,
                                                 float* __restrict__ out) {
  __shared__ double redbuf[64];
  const int lane = threadIdx.x & 63;
  const int w    = threadIdx.x >> 6;

  if (stIn->done) {
    if (threadIdx.x == 0) {
      #pragma unroll
      for (int i = 0; i < 3; ++i) {
        out[4*i + 0] = (float)stIn->Rc[3*i + 0];
        out[4*i + 1] = (float)stIn->Rc[3*i + 1];
        out[4*i + 2] = (float)stIn->Rc[3*i + 2];
        out[4*i + 3] = (float)stIn->tc[i];
      }
    }
    return;
  }

  double vv[16];
  {
    const double* row = partIn + (threadIdx.x << 4);
    #pragma unroll
    for (int c = 0; c < 16; ++c) vv[c] = row[c];
  }
  #pragma unroll
  for (int q = 0; q < 16; ++q) {
    double x = vv[q];
    for (int o = 32; o > 0; o >>= 1) x += __shfl_down(x, o, 64);
    if (lane == 0) redbuf[w*16 + q] = x;
  }
  __syncthreads();

  if (threadIdx.x == 0) {
    double sm[16];
    #pragma unroll
    for (int i = 0; i < 16; ++i)
      sm[i] = redbuf[i] + redbuf[16+i] + redbuf[32+i] + redbuf[48+i];
    double Rn[9], tn[3], errnew; int dn;
    solve_compose(sm, stIn, Rn, tn, &errnew, &dn);
    #pragma unroll
    for (int i = 0; i < 3; ++i) {
      out[4*i + 0] = (float)Rn[3*i + 0];
      out[4*i + 1] = (float)Rn[3*i + 1];
      out[4*i + 2] = (float)Rn[3*i + 2];
      out[4*i + 3] = (float)tn[i];
    }
  }
}

// ---------------------------------------------------------------------------
extern "C" void kernel_launch(void* const* d_in, const int* in_sizes, int n_in,
                              void* d_out, int out_size, void* d_ws, size_t ws_size,
                              hipStream_t stream) {
  const float* p1 = (const float*)d_in[0];
  const float* p2 = (const float*)d_in[1];
  float* out = (float*)d_out;

  char* ws = (char*)d_ws;
  float4* p2aug = (float4*)ws;                            // 128 KiB
  IcpSt* st0    = (IcpSt*)(ws + 128*1024);                // slot 0
  IcpSt* st1    = (IcpSt*)(ws + 128*1024 + 256);          // slot 1
  double* part0 = (double*)(ws + 128*1024 + 1024);        // 32 KiB
  double* part1 = (double*)(ws + 128*1024 + 1024 + 32*1024);

  IcpSt* st[2]    = { st0, st1 };
  double* part[2] = { part0, part1 };

  icp_prep<<<N_PTS/256, 256, 0, stream>>>(p2, p2aug, st0);
  for (int k = 0; k < ICP_STEPS; ++k) {
    const IcpSt* stIn   = (k == 0) ? st0 : st[(k-1) & 1];
    IcpSt* stOut        = st[k & 1];
    const double* pIn   = part[(k+1) & 1];    // = part[(k-1)&1]; unused k==0
    double* pOut        = part[k & 1];
    if (k == 0) stOut = st1;                  // keep st0 (identity) intact
    icp_iter<<<NNB, 256, 0, stream>>>(p1, p2aug, stIn, stOut, pIn, pOut, k);
  }
  // state_20 in slot (20&1)=0 chain-wise; part_20 in slot 0
  icp_final<<<1, 256, 0, stream>>>(st[0], part[0], out);
}

// Round 19
// 651.932 us; speedup vs baseline: 1.2509x; 1.2320x over previous
//
#include <hip/hip_runtime.h>
#include <math.h>

#define N_PTS 8192
#define ICP_STEPS 21      // STEPLIM + 1 scan iterations
#define ICP_TOL 1e-4

#define NNB 256           // blocks; block owns 32 queries (4 waves x 8)
#define QPWv 8            // queries per wave (wave owns them end-to-end)
#define QPB 32            // queries per block
#define CH 2048           // candidates per LDS chunk (32 KiB)
#define NCH 4             // 4 * 2048 = 8192

// state_j in slot j%2; part of step k in slot k%2 (R11-proven layout)
struct IcpSt {
  double Rc[9];     // cumulative rotation (row-major): pc = Rc*p1 + tc
  double tc[3];
  double err;
  int done;
};

// ---------------------------------------------------------------------------
// prep: p2aug = (x,y,z,|b|^2) float4; st0 = identity state
// ---------------------------------------------------------------------------
__global__ __launch_bounds__(256) void icp_prep(const float* __restrict__ p2,
                                                float4* __restrict__ p2aug,
                                                IcpSt* __restrict__ st0) {
  int t = blockIdx.x * 256 + threadIdx.x;   // grid covers exactly N_PTS
  float x = p2[3*t], y = p2[3*t+1], z = p2[3*t+2];
  p2aug[t] = make_float4(x, y, z, fmaf(x, x, fmaf(y, y, z*z)));
  if (t == 0) {
    #pragma unroll
    for (int i = 0; i < 9; ++i) st0->Rc[i] = (i % 4 == 0) ? 1.0 : 0.0;
    st0->tc[0] = st0->tc[1] = st0->tc[2] = 0.0;
    st0->err = 0.0; st0->done = 0;
  }
}

// ---------------------------------------------------------------------------
// Register-only 3x3 Kabsch from raw sums (no runtime-indexed reg arrays).
// s[0]=sum dmin, s[1..3]=sum src, s[4..6]=sum dst, s[7..15]=sum src_i*dst_j.
// R = V diag(1,1,detV) U~^T (right-handed U~) == reference's sign-fixed SVD.
// ---------------------------------------------------------------------------
__device__ __forceinline__ void kabsch_solve(const double* s, double* R, double* T) {
  const double n = (double)N_PTS;
  const double c1x = s[1]/n, c1y = s[2]/n, c1z = s[3]/n;
  const double c2x = s[4]/n, c2y = s[5]/n, c2z = s[6]/n;
  const double h00 = s[7]  - n*c1x*c2x, h01 = s[8]  - n*c1x*c2y, h02 = s[9]  - n*c1x*c2z;
  const double h10 = s[10] - n*c1y*c2x, h11 = s[11] - n*c1y*c2y, h12 = s[12] - n*c1y*c2z;
  const double h20 = s[13] - n*c1z*c2x, h21 = s[14] - n*c1z*c2y, h22 = s[15] - n*c1z*c2z;

  double a00 = h00*h00 + h10*h10 + h20*h20;
  double a01 = h00*h01 + h10*h11 + h20*h21;
  double a02 = h00*h02 + h10*h12 + h20*h22;
  double a11 = h01*h01 + h11*h11 + h21*h21;
  double a12 = h01*h02 + h11*h12 + h21*h22;
  double a22 = h02*h02 + h12*h12 + h22*h22;

  double v00=1.0, v01=0.0, v02=0.0;
  double v10=0.0, v11=1.0, v12=0.0;
  double v20=0.0, v21=0.0, v22=1.0;

#define ROT3(app, aqq, apq, arp, arq, vpa, vqa, vpb, vqb, vpc, vqc)              \
  {                                                                              \
    double apq_ = apq;                                                           \
    if (fabs(apq_) > 1e-300) {                                                   \
      double tau = (aqq - app) / (2.0 * apq_);                                   \
      double tt  = (tau >= 0.0 ? 1.0 : -1.0) / (fabs(tau) + sqrt(1.0 + tau*tau));\
      double c_  = 1.0 / sqrt(1.0 + tt*tt), sn = tt * c_;                        \
      app -= tt * apq_;  aqq += tt * apq_;  apq = 0.0;                           \
      double t1 = arp, t2 = arq;                                                 \
      arp = c_*t1 - sn*t2;  arq = sn*t1 + c_*t2;                                 \
      t1 = vpa; t2 = vqa; vpa = c_*t1 - sn*t2; vqa = sn*t1 + c_*t2;              \
      t1 = vpb; t2 = vqb; vpb = c_*t1 - sn*t2; vqb = sn*t1 + c_*t2;              \
      t1 = vpc; t2 = vqc; vpc = c_*t1 - sn*t2; vqc = sn*t1 + c_*t2;              \
    }                                                                            \
  }

  #pragma unroll
  for (int sweep = 0; sweep < 6; ++sweep) {
    ROT3(a00, a11, a01, a02, a12, v00, v01, v10, v11, v20, v21);  // (0,1)
    ROT3(a00, a22, a02, a01, a12, v00, v02, v10, v12, v20, v22);  // (0,2)
    ROT3(a11, a22, a12, a01, a02, v01, v02, v11, v12, v21, v22);  // (1,2)
  }
#undef ROT3

  double l0 = a00, l1 = a11, l2 = a22;
  double e0x=v00, e0y=v10, e0z=v20;
  double e1x=v01, e1y=v11, e1z=v21;
  double e2x=v02, e2y=v12, e2z=v22;
#define CSWAP(la, lb, xa, ya, za, xb, yb, zb)                                    \
  if (lb > la) { double t_;                                                      \
    t_ = la; la = lb; lb = t_;  t_ = xa; xa = xb; xb = t_;                       \
    t_ = ya; ya = yb; yb = t_;  t_ = za; za = zb; zb = t_; }
  CSWAP(l0, l1, e0x, e0y, e0z, e1x, e1y, e1z);
  CSWAP(l0, l2, e0x, e0y, e0z, e2x, e2y, e2z);
  CSWAP(l1, l2, e1x, e1y, e1z, e2x, e2y, e2z);
#undef CSWAP

  double detV = e0x*(e1y*e2z - e1z*e2y) - e0y*(e1x*e2z - e1z*e2x)
              + e0z*(e1x*e2y - e1y*e2x);
  const double dsg = (detV >= 0.0) ? 1.0 : -1.0;

  double u0x = h00*e0x + h01*e0y + h02*e0z;
  double u0y = h10*e0x + h11*e0y + h12*e0z;
  double u0z = h20*e0x + h21*e0y + h22*e0z;
  double n0 = sqrt(u0x*u0x + u0y*u0y + u0z*u0z);
  if (!(n0 > 1e-150)) {
    R[0]=1.0; R[1]=0.0; R[2]=0.0; R[3]=0.0; R[4]=1.0; R[5]=0.0;
    R[6]=0.0; R[7]=0.0; R[8]=1.0;
    T[0]=c2x-c1x; T[1]=c2y-c1y; T[2]=c2z-c1z;
    return;
  }
  u0x /= n0; u0y /= n0; u0z /= n0;
  double u1x = h00*e1x + h01*e1y + h02*e1z;
  double u1y = h10*e1x + h11*e1y + h12*e1z;
  double u1z = h20*e1x + h21*e1y + h22*e1z;
  const double d10 = u1x*u0x + u1y*u0y + u1z*u0z;
  u1x -= d10*u0x; u1y -= d10*u0y; u1z -= d10*u0z;
  double n1 = sqrt(u1x*u1x + u1y*u1y + u1z*u1z);
  if (!(n1 > 1e-150)) {
    R[0]=1.0; R[1]=0.0; R[2]=0.0; R[3]=0.0; R[4]=1.0; R[5]=0.0;
    R[6]=0.0; R[7]=0.0; R[8]=1.0;
    T[0]=c2x-c1x; T[1]=c2y-c1y; T[2]=c2z-c1z;
    return;
  }
  u1x /= n1; u1y /= n1; u1z /= n1;
  const double u2x = u0y*u1z - u0z*u1y;
  const double u2y = u0z*u1x - u0x*u1z;
  const double u2z = u0x*u1y - u0y*u1x;

  R[0] = e0x*u0x + e1x*u1x + dsg*e2x*u2x;
  R[1] = e0x*u0y + e1x*u1y + dsg*e2x*u2y;
  R[2] = e0x*u0z + e1x*u1z + dsg*e2x*u2z;
  R[3] = e0y*u0x + e1y*u1x + dsg*e2y*u2x;
  R[4] = e0y*u0y + e1y*u1y + dsg*e2y*u2y;
  R[5] = e0y*u0z + e1y*u1z + dsg*e2y*u2z;
  R[6] = e0z*u0x + e1z*u1x + dsg*e2z*u2x;
  R[7] = e0z*u0y + e1z*u1y + dsg*e2z*u2y;
  R[8] = e0z*u0z + e1z*u1z + dsg*e2z*u2z;
  T[0] = c2x - (R[0]*c1x + R[1]*c1y + R[2]*c1z);
  T[1] = c2y - (R[3]*c1x + R[4]*c1y + R[5]*c1z);
  T[2] = c2z - (R[6]*c1x + R[7]*c1y + R[8]*c1z);
}

// solve step: sums s[16] + stIn state -> composed Rn/tn, errnew, done flag
__device__ __forceinline__ void solve_compose(const double* s, const IcpSt* stIn,
                                              double* Rn, double* tn,
                                              double* errnew, int* dn) {
  double R[9], T[3];
  kabsch_solve(s, R, T);
  double Rc[9], tc[3];
  #pragma unroll
  for (int i = 0; i < 9; ++i) Rc[i] = stIn->Rc[i];
  #pragma unroll
  for (int i = 0; i < 3; ++i) tc[i] = stIn->tc[i];
  // pc_new = R*(Rc*p1 + tc) + T = (R*Rc)*p1 + (R*tc + T)
  #pragma unroll
  for (int i = 0; i < 3; ++i) {
    #pragma unroll
    for (int j = 0; j < 3; ++j)
      Rn[3*i+j] = R[3*i+0]*Rc[0+j] + R[3*i+1]*Rc[3+j] + R[3*i+2]*Rc[6+j];
    tn[i] = R[3*i+0]*tc[0] + R[3*i+1]*tc[1] + R[3*i+2]*tc[2] + T[i];
  }
  *errnew = s[0];                           // B == 1
  *dn = (fabs(stIn->err - *errnew) < ICP_TOL) ? 1 : 0;
}

// ---------------------------------------------------------------------------
// Fused dispatch k, R18 structure MINUS the pf[8] register prefetch (R18's
// 8.2 MB WRITE_SIZE == pf spilled at the 52-VGPR cap; scratch refills cost
// ~50 us/dispatch). Chunks now stage DIRECTLY global->LDS; live regs fit
// the budget. Everything else identical to R18 (A/B discipline).
// ---------------------------------------------------------------------------
__global__ __launch_bounds__(256) void icp_iter(const float* __restrict__ p1,
                                                const float4* __restrict__ p2aug,
                                                const IcpSt* __restrict__ stIn,
                                                IcpSt* __restrict__ stOut,
                                                const double* __restrict__ partIn,
                                                double* __restrict__ partOut,
                                                const int k) {
  __shared__ float4 cand[CH];                // 32 KiB
  __shared__ double redbuf[64];              // 4 waves x 16 (solve phase)
  __shared__ double RT[12];
  __shared__ int sdone;
  __shared__ unsigned long long pkbuf[4][9]; // wave x 8 queries (+1 pad)
  __shared__ float4 qlds[QPB];
  __shared__ double pairbuf[QPB][17];        // +1 pad

  const int tid  = threadIdx.x;
  const int lane = tid & 63;
  const int w    = tid >> 6;                 // wave 0..3

  // ---- frozen? propagate state and stop (uniform; R11-proven chain) ----
  if (stIn->done) {
    if (blockIdx.x == 0 && tid == 0) {
      #pragma unroll
      for (int i = 0; i < 9; ++i) stOut->Rc[i] = stIn->Rc[i];
      #pragma unroll
      for (int i = 0; i < 3; ++i) stOut->tc[i] = stIn->tc[i];
      stOut->err = stIn->err; stOut->done = 1;
    }
    return;
  }

  // ---- solve phase for step k-1 (every block, redundant, parallel) ----
  double R0, R1, R2, R3, R4, R5, R6, R7, R8, T0, T1, T2;
  if (k > 0) {
    double vv[16];
    {
      const double* row = partIn + (tid << 4);   // 1 row per thread (2 lines)
      #pragma unroll
      for (int c = 0; c < 16; ++c) vv[c] = row[c];
    }
    #pragma unroll
    for (int q = 0; q < 16; ++q) {
      double x = vv[q];
      for (int o = 32; o > 0; o >>= 1) x += __shfl_down(x, o, 64);
      if (lane == 0) redbuf[w*16 + q] = x;
    }
    __syncthreads();
    if (tid == 0) {
      double sm[16];
      #pragma unroll
      for (int i = 0; i < 16; ++i)
        sm[i] = redbuf[i] + redbuf[16+i] + redbuf[32+i] + redbuf[48+i];
      double Rn[9], tn[3], errnew; int dn;
      solve_compose(sm, stIn, Rn, tn, &errnew, &dn);
      // stOut: 256 blocks write bitwise-identical values (benign race)
      #pragma unroll
      for (int i = 0; i < 9; ++i) stOut->Rc[i] = Rn[i];
      #pragma unroll
      for (int i = 0; i < 3; ++i) stOut->tc[i] = tn[i];
      stOut->err = errnew; stOut->done = dn;
      #pragma unroll
      for (int i = 0; i < 9; ++i) RT[i] = Rn[i];
      RT[9] = tn[0]; RT[10] = tn[1]; RT[11] = tn[2];
      sdone = dn;
    }
    __syncthreads();
    if (sdone) return;                      // step k frozen (uniform)
    R0 = RT[0]; R1 = RT[1]; R2 = RT[2];
    R3 = RT[3]; R4 = RT[4]; R5 = RT[5];
    R6 = RT[6]; R7 = RT[7]; R8 = RT[8];
    T0 = RT[9]; T1 = RT[10]; T2 = RT[11];
  } else {
    R0 = stIn->Rc[0]; R1 = stIn->Rc[1]; R2 = stIn->Rc[2];
    R3 = stIn->Rc[3]; R4 = stIn->Rc[4]; R5 = stIn->Rc[5];
    R6 = stIn->Rc[6]; R7 = stIn->Rc[7]; R8 = stIn->Rc[8];
    T0 = stIn->tc[0]; T1 = stIn->tc[1]; T2 = stIn->tc[2];
  }

  // ---- wave w owns queries qb..qb+7 end-to-end (uniform across lanes) ----
  const int qb = (blockIdx.x << 5) + (w << 3);
  float axv[QPWv], ayv[QPWv], azv[QPWv], best[QPWv];
  int bidx[QPWv];
  #pragma unroll
  for (int j = 0; j < QPWv; ++j) {
    const int q = qb + j;
    const double X = (double)p1[3*q], Y = (double)p1[3*q+1], Z = (double)p1[3*q+2];
    const float qx = (float)(R0*X + R1*Y + R2*Z + T0);  // fp32-rounded (ref pc)
    const float qy = (float)(R3*X + R4*Y + R5*Z + T1);
    const float qz = (float)(R6*X + R7*Y + R8*Z + T2);
    axv[j] = -2.f*qx; ayv[j] = -2.f*qy; azv[j] = -2.f*qz;
    best[j] = __builtin_inff(); bidx[j] = 0;
    if (lane == 0) qlds[(w << 3) + j] = make_float4(qx, qy, qz, 0.f);
  }

  // ---- scan all candidates: 4 chunks, DIRECT global->LDS staging ----
  for (int cb = 0; cb < NCH; ++cb) {
    const int cbase = cb << 11;
    #pragma unroll
    for (int kk = 0; kk < 8; ++kk)
      cand[(kk << 8) + tid] = p2aug[cbase + (kk << 8) + tid];
    __syncthreads();
    #pragma unroll 4
    for (int kk = 0; kk < 32; ++kk) {
      const int cidx = cbase + (kk << 6) + lane;
      float4 c = cand[(kk << 6) + lane];     // ds_read_b128, conflict-free
      #pragma unroll
      for (int j = 0; j < QPWv; ++j) {
        float d = fmaf(axv[j], c.x, fmaf(ayv[j], c.y, fmaf(azv[j], c.z, c.w)));
        if (d < best[j]) { best[j] = d; bidx[j] = cidx; }
      }
    }
    __syncthreads();
  }

  // ---- wave-local FINAL argmin: packed u64 butterfly (jnp tie semantics) --
  unsigned long long pk[QPWv];
  #pragma unroll
  for (int j = 0; j < QPWv; ++j) {
    unsigned u = __float_as_uint(best[j]);
    u ^= (unsigned)((int)u >> 31) | 0x80000000u;   // monotone float->uint
    pk[j] = ((unsigned long long)u << 32) | (unsigned)bidx[j];
  }
  #pragma unroll
  for (int j = 0; j < QPWv; ++j) {
    #pragma unroll
    for (int o = 1; o < 64; o <<= 1) {
      unsigned long long other = __shfl_xor(pk[j], o, 64);
      pk[j] = (other < pk[j]) ? other : pk[j];
    }
  }
  if (lane == 0) {
    #pragma unroll
    for (int j = 0; j < QPWv; ++j) pkbuf[w][j] = pk[j];
  }
  __syncthreads();

  // ---- pair sums: tid<32 handles one query (LDS-indexed, static) ----
  if (tid < QPB) {
    const unsigned long long m = pkbuf[tid >> 3][tid & 7];
    const unsigned idx = (unsigned)(m & 0xffffffffull);
    const float4 q4 = qlds[tid];
    const float4 b4 = p2aug[idx];            // L2-resident gather
    const double ax = q4.x, ay = q4.y, az = q4.z;
    const double bx = b4.x, by = b4.y, bz = b4.z;
    const double d2 = (ax*ax + ay*ay + az*az) + (bx*bx + by*by + bz*bz)
                    - 2.0*(ax*bx + ay*by + az*bz);
    pairbuf[tid][0]  = sqrt(fmax(d2, 1e-12));
    pairbuf[tid][1]  = ax;    pairbuf[tid][2]  = ay;    pairbuf[tid][3]  = az;
    pairbuf[tid][4]  = bx;    pairbuf[tid][5]  = by;    pairbuf[tid][6]  = bz;
    pairbuf[tid][7]  = ax*bx; pairbuf[tid][8]  = ax*by; pairbuf[tid][9]  = ax*bz;
    pairbuf[tid][10] = ay*bx; pairbuf[tid][11] = ay*by; pairbuf[tid][12] = ay*bz;
    pairbuf[tid][13] = az*bx; pairbuf[tid][14] = az*by; pairbuf[tid][15] = az*bz;
  }
  __syncthreads();

  // ---- 16 column sums -> plain stores to this block's part row ----
  if (tid < 16) {
    double s = 0.0;
    #pragma unroll
    for (int i = 0; i < QPB; ++i) s += pairbuf[i][tid];
    partOut[(blockIdx.x << 4) + tid] = s;
  }
}

// ---------------------------------------------------------------------------
// final (1 block x 256): solve step 20 (if still active) and emit [R|t] 3x4.
// One-time single-CU read of 512 lines (~40us once) -- acceptable.
// ---------------------------------------------------------------------------
__global__ __launch_bounds__(256) void icp_final(const IcpSt* __restrict__ stIn,
                                                 const double* __restrict__ partIn,
                                                 float* __restrict__ out) {
  __shared__ double redbuf[64];
  const int lane = threadIdx.x & 63;
  const int w    = threadIdx.x >> 6;

  if (stIn->done) {
    if (threadIdx.x == 0) {
      #pragma unroll
      for (int i = 0; i < 3; ++i) {
        out[4*i + 0] = (float)stIn->Rc[3*i + 0];
        out[4*i + 1] = (float)stIn->Rc[3*i + 1];
        out[4*i + 2] = (float)stIn->Rc[3*i + 2];
        out[4*i + 3] = (float)stIn->tc[i];
      }
    }
    return;
  }

  double vv[16];
  {
    const double* row = partIn + (threadIdx.x << 4);
    #pragma unroll
    for (int c = 0; c < 16; ++c) vv[c] = row[c];
  }
  #pragma unroll
  for (int q = 0; q < 16; ++q) {
    double x = vv[q];
    for (int o = 32; o > 0; o >>= 1) x += __shfl_down(x, o, 64);
    if (lane == 0) redbuf[w*16 + q] = x;
  }
  __syncthreads();

  if (threadIdx.x == 0) {
    double sm[16];
    #pragma unroll
    for (int i = 0; i < 16; ++i)
      sm[i] = redbuf[i] + redbuf[16+i] + redbuf[32+i] + redbuf[48+i];
    double Rn[9], tn[3], errnew; int dn;
    solve_compose(sm, stIn, Rn, tn, &errnew, &dn);
    #pragma unroll
    for (int i = 0; i < 3; ++i) {
      out[4*i + 0] = (float)Rn[3*i + 0];
      out[4*i + 1] = (float)Rn[3*i + 1];
      out[4*i + 2] = (float)Rn[3*i + 2];
      out[4*i + 3] = (float)tn[i];
    }
  }
}

// ---------------------------------------------------------------------------
extern "C" void kernel_launch(void* const* d_in, const int* in_sizes, int n_in,
                              void* d_out, int out_size, void* d_ws, size_t ws_size,
                              hipStream_t stream) {
  const float* p1 = (const float*)d_in[0];
  const float* p2 = (const float*)d_in[1];
  float* out = (float*)d_out;

  char* ws = (char*)d_ws;
  float4* p2aug = (float4*)ws;                            // 128 KiB
  IcpSt* st0    = (IcpSt*)(ws + 128*1024);                // slot 0
  IcpSt* st1    = (IcpSt*)(ws + 128*1024 + 256);          // slot 1
  double* part0 = (double*)(ws + 128*1024 + 1024);        // 32 KiB
  double* part1 = (double*)(ws + 128*1024 + 1024 + 32*1024);

  IcpSt* st[2]    = { st0, st1 };
  double* part[2] = { part0, part1 };

  icp_prep<<<N_PTS/256, 256, 0, stream>>>(p2, p2aug, st0);
  for (int k = 0; k < ICP_STEPS; ++k) {
    const IcpSt* stIn   = (k == 0) ? st0 : st[(k-1) & 1];
    IcpSt* stOut        = st[k & 1];
    const double* pIn   = part[(k+1) & 1];    // = part[(k-1)&1]; unused k==0
    double* pOut        = part[k & 1];
    if (k == 0) stOut = st1;                  // keep st0 (identity) intact
    icp_iter<<<NNB, 256, 0, stream>>>(p1, p2aug, stIn, stOut, pIn, pOut, k);
  }
  // state_20 in slot (20&1)=0 chain-wise; part_20 in slot 0
  icp_final<<<1, 256, 0, stream>>>(st[0], part[0], out);
}

// Round 20
// 649.823 us; speedup vs baseline: 1.2549x; 1.0032x over previous
//
#include <hip/hip_runtime.h>
#include <math.h>

#define N_PTS 8192
#define ICP_STEPS 21      // STEPLIM + 1 scan iterations
#define ICP_TOL 1e-4

#define NNB 256           // blocks; block owns 32 queries (4 waves x 8)
#define QPWv 8            // queries per wave (wave owns them end-to-end)
#define QPB 32            // queries per block
#define CH 2048           // candidates per LDS chunk (32 KiB)
#define NCH 4             // 4 * 2048 = 8192

// state_j in slot j%2; part of step k in slot k%2 (R11-proven layout)
struct IcpSt {
  double Rc[9];     // cumulative rotation (row-major): pc = Rc*p1 + tc
  double tc[3];
  double err;
  int done;
};

// ---------------------------------------------------------------------------
// prep: p2aug = (x,y,z,|b|^2) float4; st0 = identity state
// ---------------------------------------------------------------------------
__global__ __launch_bounds__(256) void icp_prep(const float* __restrict__ p2,
                                                float4* __restrict__ p2aug,
                                                IcpSt* __restrict__ st0) {
  int t = blockIdx.x * 256 + threadIdx.x;   // grid covers exactly N_PTS
  float x = p2[3*t], y = p2[3*t+1], z = p2[3*t+2];
  p2aug[t] = make_float4(x, y, z, fmaf(x, x, fmaf(y, y, z*z)));
  if (t == 0) {
    #pragma unroll
    for (int i = 0; i < 9; ++i) st0->Rc[i] = (i % 4 == 0) ? 1.0 : 0.0;
    st0->tc[0] = st0->tc[1] = st0->tc[2] = 0.0;
    st0->err = 0.0; st0->done = 0;
  }
}

// ---------------------------------------------------------------------------
// Register-only 3x3 Kabsch from raw sums (no runtime-indexed reg arrays).
// s[0]=sum dmin, s[1..3]=sum src, s[4..6]=sum dst, s[7..15]=sum src_i*dst_j.
// R = V diag(1,1,detV) U~^T (right-handed U~) == reference's sign-fixed SVD.
// ---------------------------------------------------------------------------
__device__ __forceinline__ void kabsch_solve(const double* s, double* R, double* T) {
  const double n = (double)N_PTS;
  const double c1x = s[1]/n, c1y = s[2]/n, c1z = s[3]/n;
  const double c2x = s[4]/n, c2y = s[5]/n, c2z = s[6]/n;
  const double h00 = s[7]  - n*c1x*c2x, h01 = s[8]  - n*c1x*c2y, h02 = s[9]  - n*c1x*c2z;
  const double h10 = s[10] - n*c1y*c2x, h11 = s[11] - n*c1y*c2y, h12 = s[12] - n*c1y*c2z;
  const double h20 = s[13] - n*c1z*c2x, h21 = s[14] - n*c1z*c2y, h22 = s[15] - n*c1z*c2z;

  double a00 = h00*h00 + h10*h10 + h20*h20;
  double a01 = h00*h01 + h10*h11 + h20*h21;
  double a02 = h00*h02 + h10*h12 + h20*h22;
  double a11 = h01*h01 + h11*h11 + h21*h21;
  double a12 = h01*h02 + h11*h12 + h21*h22;
  double a22 = h02*h02 + h12*h12 + h22*h22;

  double v00=1.0, v01=0.0, v02=0.0;
  double v10=0.0, v11=1.0, v12=0.0;
  double v20=0.0, v21=0.0, v22=1.0;

#define ROT3(app, aqq, apq, arp, arq, vpa, vqa, vpb, vqb, vpc, vqc)              \
  {                                                                              \
    double apq_ = apq;                                                           \
    if (fabs(apq_) > 1e-300) {                                                   \
      double tau = (aqq - app) / (2.0 * apq_);                                   \
      double tt  = (tau >= 0.0 ? 1.0 : -1.0) / (fabs(tau) + sqrt(1.0 + tau*tau));\
      double c_  = 1.0 / sqrt(1.0 + tt*tt), sn = tt * c_;                        \
      app -= tt * apq_;  aqq += tt * apq_;  apq = 0.0;                           \
      double t1 = arp, t2 = arq;                                                 \
      arp = c_*t1 - sn*t2;  arq = sn*t1 + c_*t2;                                 \
      t1 = vpa; t2 = vqa; vpa = c_*t1 - sn*t2; vqa = sn*t1 + c_*t2;              \
      t1 = vpb; t2 = vqb; vpb = c_*t1 - sn*t2; vqb = sn*t1 + c_*t2;              \
      t1 = vpc; t2 = vqc; vpc = c_*t1 - sn*t2; vqc = sn*t1 + c_*t2;              \
    }                                                                            \
  }

  #pragma unroll
  for (int sweep = 0; sweep < 6; ++sweep) {
    ROT3(a00, a11, a01, a02, a12, v00, v01, v10, v11, v20, v21);  // (0,1)
    ROT3(a00, a22, a02, a01, a12, v00, v02, v10, v12, v20, v22);  // (0,2)
    ROT3(a11, a22, a12, a01, a02, v01, v02, v11, v12, v21, v22);  // (1,2)
  }
#undef ROT3

  double l0 = a00, l1 = a11, l2 = a22;
  double e0x=v00, e0y=v10, e0z=v20;
  double e1x=v01, e1y=v11, e1z=v21;
  double e2x=v02, e2y=v12, e2z=v22;
#define CSWAP(la, lb, xa, ya, za, xb, yb, zb)                                    \
  if (lb > la) { double t_;                                                      \
    t_ = la; la = lb; lb = t_;  t_ = xa; xa = xb; xb = t_;                       \
    t_ = ya; ya = yb; yb = t_;  t_ = za; za = zb; zb = t_; }
  CSWAP(l0, l1, e0x, e0y, e0z, e1x, e1y, e1z);
  CSWAP(l0, l2, e0x, e0y, e0z, e2x, e2y, e2z);
  CSWAP(l1, l2, e1x, e1y, e1z, e2x, e2y, e2z);
#undef CSWAP

  double detV = e0x*(e1y*e2z - e1z*e2y) - e0y*(e1x*e2z - e1z*e2x)
              + e0z*(e1x*e2y - e1y*e2x);
  const double dsg = (detV >= 0.0) ? 1.0 : -1.0;

  double u0x = h00*e0x + h01*e0y + h02*e0z;
  double u0y = h10*e0x + h11*e0y + h12*e0z;
  double u0z = h20*e0x + h21*e0y + h22*e0z;
  double n0 = sqrt(u0x*u0x + u0y*u0y + u0z*u0z);
  if (!(n0 > 1e-150)) {
    R[0]=1.0; R[1]=0.0; R[2]=0.0; R[3]=0.0; R[4]=1.0; R[5]=0.0;
    R[6]=0.0; R[7]=0.0; R[8]=1.0;
    T[0]=c2x-c1x; T[1]=c2y-c1y; T[2]=c2z-c1z;
    return;
  }
  u0x /= n0; u0y /= n0; u0z /= n0;
  double u1x = h00*e1x + h01*e1y + h02*e1z;
  double u1y = h10*e1x + h11*e1y + h12*e1z;
  double u1z = h20*e1x + h21*e1y + h22*e1z;
  const double d10 = u1x*u0x + u1y*u0y + u1z*u0z;
  u1x -= d10*u0x; u1y -= d10*u0y; u1z -= d10*u0z;
  double n1 = sqrt(u1x*u1x + u1y*u1y + u1z*u1z);
  if (!(n1 > 1e-150)) {
    R[0]=1.0; R[1]=0.0; R[2]=0.0; R[3]=0.0; R[4]=1.0; R[5]=0.0;
    R[6]=0.0; R[7]=0.0; R[8]=1.0;
    T[0]=c2x-c1x; T[1]=c2y-c1y; T[2]=c2z-c1z;
    return;
  }
  u1x /= n1; u1y /= n1; u1z /= n1;
  const double u2x = u0y*u1z - u0z*u1y;
  const double u2y = u0z*u1x - u0x*u1z;
  const double u2z = u0x*u1y - u0y*u1x;

  R[0] = e0x*u0x + e1x*u1x + dsg*e2x*u2x;
  R[1] = e0x*u0y + e1x*u1y + dsg*e2x*u2y;
  R[2] = e0x*u0z + e1x*u1z + dsg*e2x*u2z;
  R[3] = e0y*u0x + e1y*u1x + dsg*e2y*u2x;
  R[4] = e0y*u0y + e1y*u1y + dsg*e2y*u2y;
  R[5] = e0y*u0z + e1y*u1z + dsg*e2y*u2z;
  R[6] = e0z*u0x + e1z*u1x + dsg*e2z*u2x;
  R[7] = e0z*u0y + e1z*u1y + dsg*e2z*u2y;
  R[8] = e0z*u0z + e1z*u1z + dsg*e2z*u2z;
  T[0] = c2x - (R[0]*c1x + R[1]*c1y + R[2]*c1z);
  T[1] = c2y - (R[3]*c1x + R[4]*c1y + R[5]*c1z);
  T[2] = c2z - (R[6]*c1x + R[7]*c1y + R[8]*c1z);
}

// solve step: sums s[16] + stIn state -> composed Rn/tn, errnew, done flag
__device__ __forceinline__ void solve_compose(const double* s, const IcpSt* stIn,
                                              double* Rn, double* tn,
                                              double* errnew, int* dn) {
  double R[9], T[3];
  kabsch_solve(s, R, T);
  double Rc[9], tc[3];
  #pragma unroll
  for (int i = 0; i < 9; ++i) Rc[i] = stIn->Rc[i];
  #pragma unroll
  for (int i = 0; i < 3; ++i) tc[i] = stIn->tc[i];
  // pc_new = R*(Rc*p1 + tc) + T = (R*Rc)*p1 + (R*tc + T)
  #pragma unroll
  for (int i = 0; i < 3; ++i) {
    #pragma unroll
    for (int j = 0; j < 3; ++j)
      Rn[3*i+j] = R[3*i+0]*Rc[0+j] + R[3*i+1]*Rc[3+j] + R[3*i+2]*Rc[6+j];
    tn[i] = R[3*i+0]*tc[0] + R[3*i+1]*tc[1] + R[3*i+2]*tc[2] + T[i];
  }
  *errnew = s[0];                           // B == 1
  *dn = (fabs(stIn->err - *errnew) < ICP_TOL) ? 1 : 0;
}

// ---------------------------------------------------------------------------
// Fused dispatch k, R19 structure with ONE change: only blockIdx.x == 0
// writes stOut. R19's 60us despite no spills == 256 blocks plain-storing
// bitwise-identical state to the SAME cacheline -- same-line stores from
// 256 CUs serialize at the coherence point like R10's 256-deep RMW chain
// (~38us). All blocks still compute the solve redundantly for their own
// registers (no new dependency); only one ever stores it.
// ---------------------------------------------------------------------------
__global__ __launch_bounds__(256) void icp_iter(const float* __restrict__ p1,
                                                const float4* __restrict__ p2aug,
                                                const IcpSt* __restrict__ stIn,
                                                IcpSt* __restrict__ stOut,
                                                const double* __restrict__ partIn,
                                                double* __restrict__ partOut,
                                                const int k) {
  __shared__ float4 cand[CH];                // 32 KiB
  __shared__ double redbuf[64];              // 4 waves x 16 (solve phase)
  __shared__ double RT[12];
  __shared__ int sdone;
  __shared__ unsigned long long pkbuf[4][9]; // wave x 8 queries (+1 pad)
  __shared__ float4 qlds[QPB];
  __shared__ double pairbuf[QPB][17];        // +1 pad

  const int tid  = threadIdx.x;
  const int lane = tid & 63;
  const int w    = tid >> 6;                 // wave 0..3

  // ---- frozen? propagate state and stop (uniform; single writer) ----
  if (stIn->done) {
    if (blockIdx.x == 0 && tid == 0) {
      #pragma unroll
      for (int i = 0; i < 9; ++i) stOut->Rc[i] = stIn->Rc[i];
      #pragma unroll
      for (int i = 0; i < 3; ++i) stOut->tc[i] = stIn->tc[i];
      stOut->err = stIn->err; stOut->done = 1;
    }
    return;
  }

  // ---- solve phase for step k-1 (computed by all; STORED by block 0) ----
  double R0, R1, R2, R3, R4, R5, R6, R7, R8, T0, T1, T2;
  if (k > 0) {
    double vv[16];
    {
      const double* row = partIn + (tid << 4);   // 1 row per thread (2 lines)
      #pragma unroll
      for (int c = 0; c < 16; ++c) vv[c] = row[c];
    }
    #pragma unroll
    for (int q = 0; q < 16; ++q) {
      double x = vv[q];
      for (int o = 32; o > 0; o >>= 1) x += __shfl_down(x, o, 64);
      if (lane == 0) redbuf[w*16 + q] = x;
    }
    __syncthreads();
    if (tid == 0) {
      double sm[16];
      #pragma unroll
      for (int i = 0; i < 16; ++i)
        sm[i] = redbuf[i] + redbuf[16+i] + redbuf[32+i] + redbuf[48+i];
      double Rn[9], tn[3], errnew; int dn;
      solve_compose(sm, stIn, Rn, tn, &errnew, &dn);
      if (blockIdx.x == 0) {                // SINGLE writer (the fix)
        #pragma unroll
        for (int i = 0; i < 9; ++i) stOut->Rc[i] = Rn[i];
        #pragma unroll
        for (int i = 0; i < 3; ++i) stOut->tc[i] = tn[i];
        stOut->err = errnew; stOut->done = dn;
      }
      #pragma unroll
      for (int i = 0; i < 9; ++i) RT[i] = Rn[i];
      RT[9] = tn[0]; RT[10] = tn[1]; RT[11] = tn[2];
      sdone = dn;
    }
    __syncthreads();
    if (sdone) return;                      // step k frozen (uniform)
    R0 = RT[0]; R1 = RT[1]; R2 = RT[2];
    R3 = RT[3]; R4 = RT[4]; R5 = RT[5];
    R6 = RT[6]; R7 = RT[7]; R8 = RT[8];
    T0 = RT[9]; T1 = RT[10]; T2 = RT[11];
  } else {
    R0 = stIn->Rc[0]; R1 = stIn->Rc[1]; R2 = stIn->Rc[2];
    R3 = stIn->Rc[3]; R4 = stIn->Rc[4]; R5 = stIn->Rc[5];
    R6 = stIn->Rc[6]; R7 = stIn->Rc[7]; R8 = stIn->Rc[8];
    T0 = stIn->tc[0]; T1 = stIn->tc[1]; T2 = stIn->tc[2];
  }

  // ---- wave w owns queries qb..qb+7 end-to-end (uniform across lanes) ----
  const int qb = (blockIdx.x << 5) + (w << 3);
  float axv[QPWv], ayv[QPWv], azv[QPWv], best[QPWv];
  int bidx[QPWv];
  #pragma unroll
  for (int j = 0; j < QPWv; ++j) {
    const int q = qb + j;
    const double X = (double)p1[3*q], Y = (double)p1[3*q+1], Z = (double)p1[3*q+2];
    const float qx = (float)(R0*X + R1*Y + R2*Z + T0);  // fp32-rounded (ref pc)
    const float qy = (float)(R3*X + R4*Y + R5*Z + T1);
    const float qz = (float)(R6*X + R7*Y + R8*Z + T2);
    axv[j] = -2.f*qx; ayv[j] = -2.f*qy; azv[j] = -2.f*qz;
    best[j] = __builtin_inff(); bidx[j] = 0;
    if (lane == 0) qlds[(w << 3) + j] = make_float4(qx, qy, qz, 0.f);
  }

  // ---- scan all candidates: 4 chunks, DIRECT global->LDS staging ----
  for (int cb = 0; cb < NCH; ++cb) {
    const int cbase = cb << 11;
    #pragma unroll
    for (int kk = 0; kk < 8; ++kk)
      cand[(kk << 8) + tid] = p2aug[cbase + (kk << 8) + tid];
    __syncthreads();
    #pragma unroll 4
    for (int kk = 0; kk < 32; ++kk) {
      const int cidx = cbase + (kk << 6) + lane;
      float4 c = cand[(kk << 6) + lane];     // ds_read_b128, conflict-free
      #pragma unroll
      for (int j = 0; j < QPWv; ++j) {
        float d = fmaf(axv[j], c.x, fmaf(ayv[j], c.y, fmaf(azv[j], c.z, c.w)));
        if (d < best[j]) { best[j] = d; bidx[j] = cidx; }
      }
    }
    __syncthreads();
  }

  // ---- wave-local FINAL argmin: packed u64 butterfly (jnp tie semantics) --
  unsigned long long pk[QPWv];
  #pragma unroll
  for (int j = 0; j < QPWv; ++j) {
    unsigned u = __float_as_uint(best[j]);
    u ^= (unsigned)((int)u >> 31) | 0x80000000u;   // monotone float->uint
    pk[j] = ((unsigned long long)u << 32) | (unsigned)bidx[j];
  }
  #pragma unroll
  for (int j = 0; j < QPWv; ++j) {
    #pragma unroll
    for (int o = 1; o < 64; o <<= 1) {
      unsigned long long other = __shfl_xor(pk[j], o, 64);
      pk[j] = (other < pk[j]) ? other : pk[j];
    }
  }
  if (lane == 0) {
    #pragma unroll
    for (int j = 0; j < QPWv; ++j) pkbuf[w][j] = pk[j];
  }
  __syncthreads();

  // ---- pair sums: tid<32 handles one query (LDS-indexed, static) ----
  if (tid < QPB) {
    const unsigned long long m = pkbuf[tid >> 3][tid & 7];
    const unsigned idx = (unsigned)(m & 0xffffffffull);
    const float4 q4 = qlds[tid];
    const float4 b4 = p2aug[idx];            // L2-resident gather
    const double ax = q4.x, ay = q4.y, az = q4.z;
    const double bx = b4.x, by = b4.y, bz = b4.z;
    const double d2 = (ax*ax + ay*ay + az*az) + (bx*bx + by*by + bz*bz)
                    - 2.0*(ax*bx + ay*by + az*bz);
    pairbuf[tid][0]  = sqrt(fmax(d2, 1e-12));
    pairbuf[tid][1]  = ax;    pairbuf[tid][2]  = ay;    pairbuf[tid][3]  = az;
    pairbuf[tid][4]  = bx;    pairbuf[tid][5]  = by;    pairbuf[tid][6]  = bz;
    pairbuf[tid][7]  = ax*bx; pairbuf[tid][8]  = ax*by; pairbuf[tid][9]  = ax*bz;
    pairbuf[tid][10] = ay*bx; pairbuf[tid][11] = ay*by; pairbuf[tid][12] = ay*bz;
    pairbuf[tid][13] = az*bx; pairbuf[tid][14] = az*by; pairbuf[tid][15] = az*bz;
  }
  __syncthreads();

  // ---- 16 column sums -> plain stores to this block's part row ----
  if (tid < 16) {
    double s = 0.0;
    #pragma unroll
    for (int i = 0; i < QPB; ++i) s += pairbuf[i][tid];
    partOut[(blockIdx.x << 4) + tid] = s;
  }
}

// ---------------------------------------------------------------------------
// final (1 block x 256): solve step 20 (if still active) and emit [R|t] 3x4.
// One-time single-CU read of 512 lines (~40us once) -- acceptable.
// ---------------------------------------------------------------------------
__global__ __launch_bounds__(256) void icp_final(const IcpSt* __restrict__ stIn,
                                                 const double* __restrict__ partIn,
                                                 float* __restrict__ out) {
  __shared__ double redbuf[64];
  const int lane = threadIdx.x & 63;
  const int w    = threadIdx.x >> 6;

  if (stIn->done) {
    if (threadIdx.x == 0) {
      #pragma unroll
      for (int i = 0; i < 3; ++i) {
        out[4*i + 0] = (float)stIn->Rc[3*i + 0];
        out[4*i + 1] = (float)stIn->Rc[3*i + 1];
        out[4*i + 2] = (float)stIn->Rc[3*i + 2];
        out[4*i + 3] = (float)stIn->tc[i];
      }
    }
    return;
  }

  double vv[16];
  {
    const double* row = partIn + (threadIdx.x << 4);
    #pragma unroll
    for (int c = 0; c < 16; ++c) vv[c] = row[c];
  }
  #pragma unroll
  for (int q = 0; q < 16; ++q) {
    double x = vv[q];
    for (int o = 32; o > 0; o >>= 1) x += __shfl_down(x, o, 64);
    if (lane == 0) redbuf[w*16 + q] = x;
  }
  __syncthreads();

  if (threadIdx.x == 0) {
    double sm[16];
    #pragma unroll
    for (int i = 0; i < 16; ++i)
      sm[i] = redbuf[i] + redbuf[16+i] + redbuf[32+i] + redbuf[48+i];
    double Rn[9], tn[3], errnew; int dn;
    solve_compose(sm, stIn, Rn, tn, &errnew, &dn);
    #pragma unroll
    for (int i = 0; i < 3; ++i) {
      out[4*i + 0] = (float)Rn[3*i + 0];
      out[4*i + 1] = (float)Rn[3*i + 1];
      out[4*i + 2] = (float)Rn[3*i + 2];
      out[4*i + 3] = (float)tn[i];
    }
  }
}

// ---------------------------------------------------------------------------
extern "C" void kernel_launch(void* const* d_in, const int* in_sizes, int n_in,
                              void* d_out, int out_size, void* d_ws, size_t ws_size,
                              hipStream_t stream) {
  const float* p1 = (const float*)d_in[0];
  const float* p2 = (const float*)d_in[1];
  float* out = (float*)d_out;

  char* ws = (char*)d_ws;
  float4* p2aug = (float4*)ws;                            // 128 KiB
  IcpSt* st0    = (IcpSt*)(ws + 128*1024);                // slot 0
  IcpSt* st1    = (IcpSt*)(ws + 128*1024 + 256);          // slot 1
  double* part0 = (double*)(ws + 128*1024 + 1024);        // 32 KiB
  double* part1 = (double*)(ws + 128*1024 + 1024 + 32*1024);

  IcpSt* st[2]    = { st0, st1 };
  double* part[2] = { part0, part1 };

  icp_prep<<<N_PTS/256, 256, 0, stream>>>(p2, p2aug, st0);
  for (int k = 0; k < ICP_STEPS; ++k) {
    const IcpSt* stIn   = (k == 0) ? st0 : st[(k-1) & 1];
    IcpSt* stOut        = st[k & 1];
    const double* pIn   = part[(k+1) & 1];    // = part[(k-1)&1]; unused k==0
    double* pOut        = part[k & 1];
    if (k == 0) stOut = st1;                  // keep st0 (identity) intact
    icp_iter<<<NNB, 256, 0, stream>>>(p1, p2aug, stIn, stOut, pIn, pOut, k);
  }
  // state_20 in slot (20&1)=0 chain-wise; part_20 in slot 0
  icp_final<<<1, 256, 0, stream>>>(st[0], part[0], out);
}

// Round 21
// 616.220 us; speedup vs baseline: 1.3233x; 1.0545x over previous
//
#include <hip/hip_runtime.h>
#include <math.h>

#define N_PTS 8192
#define ICP_STEPS 21      // STEPLIM + 1 scan iterations
#define ICP_TOL 1e-4

#define NNB 256           // NN blocks; block owns 32 queries (4 waves x 8)
#define QPWv 8            // queries per wave (wave owns them end-to-end)
#define QPB 32            // queries per block
#define CH 2048           // candidates per LDS chunk (32 KiB)
#define NCH 4             // 4 * 2048 = 8192

struct IcpSt {
  double Rc[9];     // cumulative rotation (row-major): pc = Rc*p1 + tc
  double tc[3];
  double err;
  int done;
};

// ---------------------------------------------------------------------------
// prep: p2aug = (x,y,z,|b|^2) float4; ctl = identity state
// ---------------------------------------------------------------------------
__global__ __launch_bounds__(256) void icp_prep(const float* __restrict__ p2,
                                                float4* __restrict__ p2aug,
                                                IcpSt* __restrict__ ctl) {
  int t = blockIdx.x * 256 + threadIdx.x;   // grid covers exactly N_PTS
  float x = p2[3*t], y = p2[3*t+1], z = p2[3*t+2];
  p2aug[t] = make_float4(x, y, z, fmaf(x, x, fmaf(y, y, z*z)));
  if (t == 0) {
    #pragma unroll
    for (int i = 0; i < 9; ++i) ctl->Rc[i] = (i % 4 == 0) ? 1.0 : 0.0;
    ctl->tc[0] = ctl->tc[1] = ctl->tc[2] = 0.0;
    ctl->err = 0.0; ctl->done = 0;
  }
}

// ---------------------------------------------------------------------------
// NN + block pair-sums (R19/R20 NN core, standalone). 256 blk x 256 thr,
// 32 KB LDS chunked full scan; wave owns 8 queries end-to-end -> wave-local
// butterfly argmin is final; zero atomics; part[bid][16] plain stores.
// Packed u64 (ordered-dist, idx) keeps jnp.argmin tie semantics.
// ---------------------------------------------------------------------------
__global__ __launch_bounds__(256) void icp_nn(const float* __restrict__ p1,
                                              const float4* __restrict__ p2aug,
                                              const IcpSt* __restrict__ ctl,
                                              double* __restrict__ part) {
  if (ctl->done) return;                     // uniform across grid
  __shared__ float4 cand[CH];                // 32 KiB
  __shared__ unsigned long long pkbuf[4][9]; // wave x 8 queries (+1 pad)
  __shared__ float4 qlds[QPB];
  __shared__ double pairbuf[QPB][17];        // +1 pad

  const int tid  = threadIdx.x;
  const int lane = tid & 63;
  const int w    = tid >> 6;                 // wave 0..3

  const double R0 = ctl->Rc[0], R1 = ctl->Rc[1], R2 = ctl->Rc[2];
  const double R3 = ctl->Rc[3], R4 = ctl->Rc[4], R5 = ctl->Rc[5];
  const double R6 = ctl->Rc[6], R7 = ctl->Rc[7], R8 = ctl->Rc[8];
  const double T0 = ctl->tc[0], T1 = ctl->tc[1], T2 = ctl->tc[2];

  // ---- wave w owns queries qb..qb+7 end-to-end (uniform across lanes) ----
  const int qb = (blockIdx.x << 5) + (w << 3);
  float axv[QPWv], ayv[QPWv], azv[QPWv], best[QPWv];
  int bidx[QPWv];
  #pragma unroll
  for (int j = 0; j < QPWv; ++j) {
    const int q = qb + j;
    const double X = (double)p1[3*q], Y = (double)p1[3*q+1], Z = (double)p1[3*q+2];
    const float qx = (float)(R0*X + R1*Y + R2*Z + T0);  // fp32-rounded (ref pc)
    const float qy = (float)(R3*X + R4*Y + R5*Z + T1);
    const float qz = (float)(R6*X + R7*Y + R8*Z + T2);
    axv[j] = -2.f*qx; ayv[j] = -2.f*qy; azv[j] = -2.f*qz;
    best[j] = __builtin_inff(); bidx[j] = 0;
    if (lane == 0) qlds[(w << 3) + j] = make_float4(qx, qy, qz, 0.f);
  }

  // ---- scan all candidates: 4 chunks, direct global->LDS staging ----
  for (int cb = 0; cb < NCH; ++cb) {
    const int cbase = cb << 11;
    #pragma unroll
    for (int kk = 0; kk < 8; ++kk)
      cand[(kk << 8) + tid] = p2aug[cbase + (kk << 8) + tid];
    __syncthreads();
    #pragma unroll 4
    for (int kk = 0; kk < 32; ++kk) {
      const int cidx = cbase + (kk << 6) + lane;
      float4 c = cand[(kk << 6) + lane];     // ds_read_b128, conflict-free
      #pragma unroll
      for (int j = 0; j < QPWv; ++j) {
        float d = fmaf(axv[j], c.x, fmaf(ayv[j], c.y, fmaf(azv[j], c.z, c.w)));
        if (d < best[j]) { best[j] = d; bidx[j] = cidx; }
      }
    }
    __syncthreads();
  }

  // ---- wave-local FINAL argmin: packed u64 butterfly ----
  unsigned long long pk[QPWv];
  #pragma unroll
  for (int j = 0; j < QPWv; ++j) {
    unsigned u = __float_as_uint(best[j]);
    u ^= (unsigned)((int)u >> 31) | 0x80000000u;   // monotone float->uint
    pk[j] = ((unsigned long long)u << 32) | (unsigned)bidx[j];
  }
  #pragma unroll
  for (int j = 0; j < QPWv; ++j) {
    #pragma unroll
    for (int o = 1; o < 64; o <<= 1) {
      unsigned long long other = __shfl_xor(pk[j], o, 64);
      pk[j] = (other < pk[j]) ? other : pk[j];
    }
  }
  if (lane == 0) {
    #pragma unroll
    for (int j = 0; j < QPWv; ++j) pkbuf[w][j] = pk[j];
  }
  __syncthreads();

  // ---- pair sums: tid<32 handles one query (LDS-indexed, static) ----
  if (tid < QPB) {
    const unsigned long long m = pkbuf[tid >> 3][tid & 7];
    const unsigned idx = (unsigned)(m & 0xffffffffull);
    const float4 q4 = qlds[tid];
    const float4 b4 = p2aug[idx];            // L2-resident gather
    const double ax = q4.x, ay = q4.y, az = q4.z;
    const double bx = b4.x, by = b4.y, bz = b4.z;
    const double d2 = (ax*ax + ay*ay + az*az) + (bx*bx + by*by + bz*bz)
                    - 2.0*(ax*bx + ay*by + az*bz);
    pairbuf[tid][0]  = sqrt(fmax(d2, 1e-12));
    pairbuf[tid][1]  = ax;    pairbuf[tid][2]  = ay;    pairbuf[tid][3]  = az;
    pairbuf[tid][4]  = bx;    pairbuf[tid][5]  = by;    pairbuf[tid][6]  = bz;
    pairbuf[tid][7]  = ax*bx; pairbuf[tid][8]  = ax*by; pairbuf[tid][9]  = ax*bz;
    pairbuf[tid][10] = ay*bx; pairbuf[tid][11] = ay*by; pairbuf[tid][12] = ay*bz;
    pairbuf[tid][13] = az*bx; pairbuf[tid][14] = az*by; pairbuf[tid][15] = az*bz;
  }
  __syncthreads();

  // ---- 16 column sums -> plain stores to this block's part row ----
  if (tid < 16) {
    double s = 0.0;
    #pragma unroll
    for (int i = 0; i < QPB; ++i) s += pairbuf[i][tid];
    part[(blockIdx.x << 4) + tid] = s;
  }
}

// ---------------------------------------------------------------------------
// red: 16 blocks x 64 threads. Block r reduces part rows 16r..16r+15
// (32 dirty lines, read in PARALLEL across 16 CUs) -> red[r][16].
// Thread t = 16*j + c: sums col c over rows {16r+j, +4, +8, +12}, then
// shfl-reduce over the 4 j-groups -> lanes 0..15 hold the 16 col sums.
// ---------------------------------------------------------------------------
__global__ __launch_bounds__(64) void icp_red(const IcpSt* __restrict__ ctl,
                                              const double* __restrict__ part,
                                              double* __restrict__ red) {
  if (ctl->done) return;
  const int t = threadIdx.x;                 // 0..63
  const int c = t & 15;
  const int j = t >> 4;                      // 0..3
  const int rbase = (blockIdx.x << 4);       // 16 rows per block
  double s = part[((rbase + j)      << 4) + c]
           + part[((rbase + j + 4)  << 4) + c]
           + part[((rbase + j + 8)  << 4) + c]
           + part[((rbase + j + 12) << 4) + c];
  s += __shfl_down(s, 32, 64);
  s += __shfl_down(s, 16, 64);
  if (t < 16) red[(blockIdx.x << 4) + t] = s;
}

// ---------------------------------------------------------------------------
// Register-only 3x3 Kabsch from raw sums (no runtime-indexed reg arrays).
// ---------------------------------------------------------------------------
__device__ __forceinline__ void kabsch_solve(const double* s, double* R, double* T) {
  const double n = (double)N_PTS;
  const double c1x = s[1]/n, c1y = s[2]/n, c1z = s[3]/n;
  const double c2x = s[4]/n, c2y = s[5]/n, c2z = s[6]/n;
  const double h00 = s[7]  - n*c1x*c2x, h01 = s[8]  - n*c1x*c2y, h02 = s[9]  - n*c1x*c2z;
  const double h10 = s[10] - n*c1y*c2x, h11 = s[11] - n*c1y*c2y, h12 = s[12] - n*c1y*c2z;
  const double h20 = s[13] - n*c1z*c2x, h21 = s[14] - n*c1z*c2y, h22 = s[15] - n*c1z*c2z;

  double a00 = h00*h00 + h10*h10 + h20*h20;
  double a01 = h00*h01 + h10*h11 + h20*h21;
  double a02 = h00*h02 + h10*h12 + h20*h22;
  double a11 = h01*h01 + h11*h11 + h21*h21;
  double a12 = h01*h02 + h11*h12 + h21*h22;
  double a22 = h02*h02 + h12*h12 + h22*h22;

  double v00=1.0, v01=0.0, v02=0.0;
  double v10=0.0, v11=1.0, v12=0.0;
  double v20=0.0, v21=0.0, v22=1.0;

#define ROT3(app, aqq, apq, arp, arq, vpa, vqa, vpb, vqb, vpc, vqc)              \
  {                                                                              \
    double apq_ = apq;                                                           \
    if (fabs(apq_) > 1e-300) {                                                   \
      double tau = (aqq - app) / (2.0 * apq_);                                   \
      double tt  = (tau >= 0.0 ? 1.0 : -1.0) / (fabs(tau) + sqrt(1.0 + tau*tau));\
      double c_  = 1.0 / sqrt(1.0 + tt*tt), sn = tt * c_;                        \
      app -= tt * apq_;  aqq += tt * apq_;  apq = 0.0;                           \
      double t1 = arp, t2 = arq;                                                 \
      arp = c_*t1 - sn*t2;  arq = sn*t1 + c_*t2;                                 \
      t1 = vpa; t2 = vqa; vpa = c_*t1 - sn*t2; vqa = sn*t1 + c_*t2;              \
      t1 = vpb; t2 = vqb; vpb = c_*t1 - sn*t2; vqb = sn*t1 + c_*t2;              \
      t1 = vpc; t2 = vqc; vpc = c_*t1 - sn*t2; vqc = sn*t1 + c_*t2;              \
    }                                                                            \
  }

  #pragma unroll
  for (int sweep = 0; sweep < 6; ++sweep) {
    ROT3(a00, a11, a01, a02, a12, v00, v01, v10, v11, v20, v21);  // (0,1)
    ROT3(a00, a22, a02, a01, a12, v00, v02, v10, v12, v20, v22);  // (0,2)
    ROT3(a11, a22, a12, a01, a02, v01, v02, v11, v12, v21, v22);  // (1,2)
  }
#undef ROT3

  double l0 = a00, l1 = a11, l2 = a22;
  double e0x=v00, e0y=v10, e0z=v20;
  double e1x=v01, e1y=v11, e1z=v21;
  double e2x=v02, e2y=v12, e2z=v22;
#define CSWAP(la, lb, xa, ya, za, xb, yb, zb)                                    \
  if (lb > la) { double t_;                                                      \
    t_ = la; la = lb; lb = t_;  t_ = xa; xa = xb; xb = t_;                       \
    t_ = ya; ya = yb; yb = t_;  t_ = za; za = zb; zb = t_; }
  CSWAP(l0, l1, e0x, e0y, e0z, e1x, e1y, e1z);
  CSWAP(l0, l2, e0x, e0y, e0z, e2x, e2y, e2z);
  CSWAP(l1, l2, e1x, e1y, e1z, e2x, e2y, e2z);
#undef CSWAP

  double detV = e0x*(e1y*e2z - e1z*e2y) - e0y*(e1x*e2z - e1z*e2x)
              + e0z*(e1x*e2y - e1y*e2x);
  const double dsg = (detV >= 0.0) ? 1.0 : -1.0;

  double u0x = h00*e0x + h01*e0y + h02*e0z;
  double u0y = h10*e0x + h11*e0y + h12*e0z;
  double u0z = h20*e0x + h21*e0y + h22*e0z;
  double n0 = sqrt(u0x*u0x + u0y*u0y + u0z*u0z);
  if (!(n0 > 1e-150)) {
    R[0]=1.0; R[1]=0.0; R[2]=0.0; R[3]=0.0; R[4]=1.0; R[5]=0.0;
    R[6]=0.0; R[7]=0.0; R[8]=1.0;
    T[0]=c2x-c1x; T[1]=c2y-c1y; T[2]=c2z-c1z;
    return;
  }
  u0x /= n0; u0y /= n0; u0z /= n0;
  double u1x = h00*e1x + h01*e1y + h02*e1z;
  double u1y = h10*e1x + h11*e1y + h12*e1z;
  double u1z = h20*e1x + h21*e1y + h22*e1z;
  const double d10 = u1x*u0x + u1y*u0y + u1z*u0z;
  u1x -= d10*u0x; u1y -= d10*u0y; u1z -= d10*u0z;
  double n1 = sqrt(u1x*u1x + u1y*u1y + u1z*u1z);
  if (!(n1 > 1e-150)) {
    R[0]=1.0; R[1]=0.0; R[2]=0.0; R[3]=0.0; R[4]=1.0; R[5]=0.0;
    R[6]=0.0; R[7]=0.0; R[8]=1.0;
    T[0]=c2x-c1x; T[1]=c2y-c1y; T[2]=c2z-c1z;
    return;
  }
  u1x /= n1; u1y /= n1; u1z /= n1;
  const double u2x = u0y*u1z - u0z*u1y;
  const double u2y = u0z*u1x - u0x*u1z;
  const double u2z = u0x*u1y - u0y*u1x;

  R[0] = e0x*u0x + e1x*u1x + dsg*e2x*u2x;
  R[1] = e0x*u0y + e1x*u1y + dsg*e2x*u2y;
  R[2] = e0x*u0z + e1x*u1z + dsg*e2x*u2z;
  R[3] = e0y*u0x + e1y*u1x + dsg*e2y*u2x;
  R[4] = e0y*u0y + e1y*u1y + dsg*e2y*u2y;
  R[5] = e0y*u0z + e1y*u1z + dsg*e2y*u2z;
  R[6] = e0z*u0x + e1z*u1x + dsg*e2z*u2x;
  R[7] = e0z*u0y + e1z*u1y + dsg*e2z*u2y;
  R[8] = e0z*u0z + e1z*u1z + dsg*e2z*u2z;
  T[0] = c2x - (R[0]*c1x + R[1]*c1y + R[2]*c1z);
  T[1] = c2y - (R[3]*c1x + R[4]*c1y + R[5]*c1z);
  T[2] = c2z - (R[6]*c1x + R[7]*c1y + R[8]*c1z);
}

// ---------------------------------------------------------------------------
// solve (1 block x 64): reduce red[16][16] (32 dirty lines ~1.5us), register
// Kabsch, compose cumulative transform, done-logic, write ctl + out.
// ---------------------------------------------------------------------------
__global__ __launch_bounds__(64) void icp_solve(IcpSt* __restrict__ ctl,
                                                const double* __restrict__ red,
                                                float* __restrict__ out) {
  if (ctl->done) return;
  __shared__ double tot[16];
  const int t = threadIdx.x;
  const int c = t & 15;
  const int j = t >> 4;                      // 0..3
  double s = red[((j)      << 4) + c]
           + red[((j + 4)  << 4) + c]
           + red[((j + 8)  << 4) + c]
           + red[((j + 12) << 4) + c];
  s += __shfl_down(s, 32, 64);
  s += __shfl_down(s, 16, 64);
  if (t < 16) tot[t] = s;
  __syncthreads();

  if (t == 0) {
    double sm[16];
    #pragma unroll
    for (int i = 0; i < 16; ++i) sm[i] = tot[i];
    double R[9], T[3];
    kabsch_solve(sm, R, T);
    // compose: pc_new = R*(Rc*p1 + tc) + T = (R*Rc)*p1 + (R*tc + T)
    double Rc[9], tc[3], Rn[9], tn[3];
    #pragma unroll
    for (int i = 0; i < 9; ++i) Rc[i] = ctl->Rc[i];
    #pragma unroll
    for (int i = 0; i < 3; ++i) tc[i] = ctl->tc[i];
    #pragma unroll
    for (int i = 0; i < 3; ++i) {
      #pragma unroll
      for (int jj = 0; jj < 3; ++jj)
        Rn[3*i+jj] = R[3*i+0]*Rc[0+jj] + R[3*i+1]*Rc[3+jj] + R[3*i+2]*Rc[6+jj];
      tn[i] = R[3*i+0]*tc[0] + R[3*i+1]*tc[1] + R[3*i+2]*tc[2] + T[i];
    }
    #pragma unroll
    for (int i = 0; i < 9; ++i) ctl->Rc[i] = Rn[i];
    #pragma unroll
    for (int i = 0; i < 3; ++i) ctl->tc[i] = tn[i];
    const double errnew = sm[0];            // B == 1
    ctl->done = (fabs(ctl->err - errnew) < ICP_TOL) ? 1 : 0;
    ctl->err  = errnew;
    // out = [Rc | tc] 3x4 (kabsch(p1, Rc*p1+tc) == (Rc,tc) exactly).
    #pragma unroll
    for (int i = 0; i < 3; ++i) {
      out[4*i + 0] = (float)Rn[3*i + 0];
      out[4*i + 1] = (float)Rn[3*i + 1];
      out[4*i + 2] = (float)Rn[3*i + 2];
      out[4*i + 3] = (float)tn[i];
    }
  }
}

// ---------------------------------------------------------------------------
extern "C" void kernel_launch(void* const* d_in, const int* in_sizes, int n_in,
                              void* d_out, int out_size, void* d_ws, size_t ws_size,
                              hipStream_t stream) {
  const float* p1 = (const float*)d_in[0];
  const float* p2 = (const float*)d_in[1];
  float* out = (float*)d_out;

  char* ws = (char*)d_ws;
  float4* p2aug = (float4*)ws;                   // 128 KiB
  IcpSt* ctl    = (IcpSt*)(ws + 128*1024);       // ~120 B
  double* part  = (double*)(ws + 132*1024);      // 32 KiB (256 x 16)
  double* red   = (double*)(ws + 168*1024);      // 2 KiB (16 x 16)

  icp_prep<<<N_PTS/256, 256, 0, stream>>>(p2, p2aug, ctl);
  for (int it = 0; it < ICP_STEPS; ++it) {
    icp_nn<<<NNB, 256, 0, stream>>>(p1, p2aug, ctl, part);
    icp_red<<<16, 64, 0, stream>>>(ctl, part, red);
    icp_solve<<<1, 64, 0, stream>>>(ctl, red, out);
  }
}

// Round 22
// 479.648 us; speedup vs baseline: 1.7002x; 1.2847x over previous
//
#include <hip/hip_runtime.h>
#include <math.h>

#define N_PTS 8192
#define ICP_STEPS 21      // STEPLIM + 1 scan iterations
#define ICP_TOL 1e-4

#define NBLK 256          // blocks (2 per CU at 512 thr / ~71 KB LDS)
#define BSIZE 512         // 8 waves
#define QPW 4             // queries per wave (wave owns them end-to-end)
#define CH 4096           // candidates per LDS chunk (64 KiB)
#define NCH 2             // 2 * 4096 = 8192
#define NSETS 16          // accumulator sets: contention <= 16-way

struct IcpCtl {
  double err;
  double Rc[9];     // cumulative rotation (row-major): pc = Rc*p1 + tc
  double tc[3];
  int done;
};

// ---------------------------------------------------------------------------
// prep: p2aug = (x,y,z,|b|^2); acc/tickets zeroed; ctl reset (every replay)
// ---------------------------------------------------------------------------
__global__ __launch_bounds__(256) void icp_prep(const float* __restrict__ p2,
                                                float4* __restrict__ p2aug,
                                                IcpCtl* __restrict__ ctl,
                                                double* __restrict__ acc,
                                                unsigned* __restrict__ gtick,
                                                unsigned* __restrict__ root) {
  int t = blockIdx.x * 256 + threadIdx.x;   // grid covers exactly N_PTS
  float x = p2[3*t], y = p2[3*t+1], z = p2[3*t+2];
  p2aug[t] = make_float4(x, y, z, fmaf(x, x, fmaf(y, y, z*z)));
  if (t < NSETS * 16) acc[t] = 0.0;
  if (t < NSETS) gtick[t << 4] = 0u;        // 16 tickets on separate lines
  if (t == 0) {
    *root = 0u;
    ctl->err = 0.0; ctl->done = 0;
    #pragma unroll
    for (int i = 0; i < 9; ++i) ctl->Rc[i] = (i % 4 == 0) ? 1.0 : 0.0;
    ctl->tc[0] = ctl->tc[1] = ctl->tc[2] = 0.0;
  }
}

// ---------------------------------------------------------------------------
// Register-only 3x3 Kabsch from raw sums (no runtime-indexed reg arrays).
// s[0]=sum dmin, s[1..3]=sum src, s[4..6]=sum dst, s[7..15]=sum src_i*dst_j.
// R = V diag(1,1,detV) U~^T (right-handed U~) == reference's sign-fixed SVD.
// ---------------------------------------------------------------------------
__device__ __forceinline__ void kabsch_solve(const double* s, double* R, double* T) {
  const double n = (double)N_PTS;
  const double c1x = s[1]/n, c1y = s[2]/n, c1z = s[3]/n;
  const double c2x = s[4]/n, c2y = s[5]/n, c2z = s[6]/n;
  const double h00 = s[7]  - n*c1x*c2x, h01 = s[8]  - n*c1x*c2y, h02 = s[9]  - n*c1x*c2z;
  const double h10 = s[10] - n*c1y*c2x, h11 = s[11] - n*c1y*c2y, h12 = s[12] - n*c1y*c2z;
  const double h20 = s[13] - n*c1z*c2x, h21 = s[14] - n*c1z*c2y, h22 = s[15] - n*c1z*c2z;

  double a00 = h00*h00 + h10*h10 + h20*h20;
  double a01 = h00*h01 + h10*h11 + h20*h21;
  double a02 = h00*h02 + h10*h12 + h20*h22;
  double a11 = h01*h01 + h11*h11 + h21*h21;
  double a12 = h01*h02 + h11*h12 + h21*h22;
  double a22 = h02*h02 + h12*h12 + h22*h22;

  double v00=1.0, v01=0.0, v02=0.0;
  double v10=0.0, v11=1.0, v12=0.0;
  double v20=0.0, v21=0.0, v22=1.0;

#define ROT3(app, aqq, apq, arp, arq, vpa, vqa, vpb, vqb, vpc, vqc)              \
  {                                                                              \
    double apq_ = apq;                                                           \
    if (fabs(apq_) > 1e-300) {                                                   \
      double tau = (aqq - app) / (2.0 * apq_);                                   \
      double tt  = (tau >= 0.0 ? 1.0 : -1.0) / (fabs(tau) + sqrt(1.0 + tau*tau));\
      double c_  = 1.0 / sqrt(1.0 + tt*tt), sn = tt * c_;                        \
      app -= tt * apq_;  aqq += tt * apq_;  apq = 0.0;                           \
      double t1 = arp, t2 = arq;                                                 \
      arp = c_*t1 - sn*t2;  arq = sn*t1 + c_*t2;                                 \
      t1 = vpa; t2 = vqa; vpa = c_*t1 - sn*t2; vqa = sn*t1 + c_*t2;              \
      t1 = vpb; t2 = vqb; vpb = c_*t1 - sn*t2; vqb = sn*t1 + c_*t2;              \
      t1 = vpc; t2 = vqc; vpc = c_*t1 - sn*t2; vqc = sn*t1 + c_*t2;              \
    }                                                                            \
  }

  #pragma unroll
  for (int sweep = 0; sweep < 6; ++sweep) {
    ROT3(a00, a11, a01, a02, a12, v00, v01, v10, v11, v20, v21);  // (0,1)
    ROT3(a00, a22, a02, a01, a12, v00, v02, v10, v12, v20, v22);  // (0,2)
    ROT3(a11, a22, a12, a01, a02, v01, v02, v11, v12, v21, v22);  // (1,2)
  }
#undef ROT3

  double l0 = a00, l1 = a11, l2 = a22;
  double e0x=v00, e0y=v10, e0z=v20;
  double e1x=v01, e1y=v11, e1z=v21;
  double e2x=v02, e2y=v12, e2z=v22;
#define CSWAP(la, lb, xa, ya, za, xb, yb, zb)                                    \
  if (lb > la) { double t_;                                                      \
    t_ = la; la = lb; lb = t_;  t_ = xa; xa = xb; xb = t_;                       \
    t_ = ya; ya = yb; yb = t_;  t_ = za; za = zb; zb = t_; }
  CSWAP(l0, l1, e0x, e0y, e0z, e1x, e1y, e1z);
  CSWAP(l0, l2, e0x, e0y, e0z, e2x, e2y, e2z);
  CSWAP(l1, l2, e1x, e1y, e1z, e2x, e2y, e2z);
#undef CSWAP

  double detV = e0x*(e1y*e2z - e1z*e2y) - e0y*(e1x*e2z - e1z*e2x)
              + e0z*(e1x*e2y - e1y*e2x);
  const double dsg = (detV >= 0.0) ? 1.0 : -1.0;

  double u0x = h00*e0x + h01*e0y + h02*e0z;
  double u0y = h10*e0x + h11*e0y + h12*e0z;
  double u0z = h20*e0x + h21*e0y + h22*e0z;
  double n0 = sqrt(u0x*u0x + u0y*u0y + u0z*u0z);
  if (!(n0 > 1e-150)) {
    R[0]=1.0; R[1]=0.0; R[2]=0.0; R[3]=0.0; R[4]=1.0; R[5]=0.0;
    R[6]=0.0; R[7]=0.0; R[8]=1.0;
    T[0]=c2x-c1x; T[1]=c2y-c1y; T[2]=c2z-c1z;
    return;
  }
  u0x /= n0; u0y /= n0; u0z /= n0;
  double u1x = h00*e1x + h01*e1y + h02*e1z;
  double u1y = h10*e1x + h11*e1y + h12*e1z;
  double u1z = h20*e1x + h21*e1y + h22*e1z;
  const double d10 = u1x*u0x + u1y*u0y + u1z*u0z;
  u1x -= d10*u0x; u1y -= d10*u0y; u1z -= d10*u0z;
  double n1 = sqrt(u1x*u1x + u1y*u1y + u1z*u1z);
  if (!(n1 > 1e-150)) {
    R[0]=1.0; R[1]=0.0; R[2]=0.0; R[3]=0.0; R[4]=1.0; R[5]=0.0;
    R[6]=0.0; R[7]=0.0; R[8]=1.0;
    T[0]=c2x-c1x; T[1]=c2y-c1y; T[2]=c2z-c1z;
    return;
  }
  u1x /= n1; u1y /= n1; u1z /= n1;
  const double u2x = u0y*u1z - u0z*u1y;
  const double u2y = u0z*u1x - u0x*u1z;
  const double u2z = u0x*u1y - u0y*u1x;

  R[0] = e0x*u0x + e1x*u1x + dsg*e2x*u2x;
  R[1] = e0x*u0y + e1x*u1y + dsg*e2x*u2y;
  R[2] = e0x*u0z + e1x*u1z + dsg*e2x*u2z;
  R[3] = e0y*u0x + e1y*u1x + dsg*e2y*u2x;
  R[4] = e0y*u0y + e1y*u1y + dsg*e2y*u2y;
  R[5] = e0y*u0z + e1y*u1z + dsg*e2y*u2z;
  R[6] = e0z*u0x + e1z*u1x + dsg*e2z*u2x;
  R[7] = e0z*u0y + e1z*u1y + dsg*e2z*u2y;
  R[8] = e0z*u0z + e1z*u1z + dsg*e2z*u2z;
  T[0] = c2x - (R[0]*c1x + R[1]*c1y + R[2]*c1z);
  T[1] = c2y - (R[3]*c1x + R[4]*c1y + R[5]*c1z);
  T[2] = c2z - (R[6]*c1x + R[7]*c1y + R[8]*c1z);
}

// ---------------------------------------------------------------------------
// One FUSED ICP iteration per dispatch (22 slots). R15 structure with the
// WG footprint HALVED: 512 thr (8 waves) + 64 KB chunked staging (2 chunks)
// instead of 1024 thr + 128 KB full stage. Wave owns 4 queries end-to-end
// (wave-local final argmin, R17-proven). Tail = R15's contention tree
// (16-way sets + padded tickets + root; solver in root-last block).
// ---------------------------------------------------------------------------
__global__ __launch_bounds__(BSIZE) void icp_step(const float* __restrict__ p1,
                                                  const float4* __restrict__ p2aug,
                                                  IcpCtl* __restrict__ ctl,
                                                  double* __restrict__ acc,
                                                  unsigned* __restrict__ gtick,
                                                  unsigned* __restrict__ root,
                                                  float* __restrict__ out) {
  if (ctl->done) return;                    // uniform across grid
  __shared__ float4 cand[CH];               // 64 KiB
  __shared__ unsigned long long pkbuf[8][5];// wave x 4 queries (+1 pad)
  __shared__ float4 qlds[32];
  __shared__ double pairbuf[32][17];        // +1 pad
  __shared__ double setbuf[16][17];         // solver: per-set sums (+1 pad)
  __shared__ double totbuf[16];
  __shared__ int solverFlag;

  const int tid  = threadIdx.x;
  const int lane = tid & 63;
  const int w    = tid >> 6;                // wave 0..7
  const int bid  = blockIdx.x;

  if (tid == 0) solverFlag = 0;

  const double R0 = ctl->Rc[0], R1 = ctl->Rc[1], R2 = ctl->Rc[2];
  const double R3 = ctl->Rc[3], R4 = ctl->Rc[4], R5 = ctl->Rc[5];
  const double R6 = ctl->Rc[6], R7 = ctl->Rc[7], R8 = ctl->Rc[8];
  const double T0 = ctl->tc[0], T1 = ctl->tc[1], T2 = ctl->tc[2];

  // ---- wave w owns queries qb..qb+3 end-to-end (uniform across lanes) ----
  const int qb = (bid << 5) + (w << 2);
  float axv[QPW], ayv[QPW], azv[QPW], best[QPW];
  int bidx[QPW];
  #pragma unroll
  for (int j = 0; j < QPW; ++j) {
    const int q = qb + j;
    const double X = (double)p1[3*q], Y = (double)p1[3*q+1], Z = (double)p1[3*q+2];
    const float qx = (float)(R0*X + R1*Y + R2*Z + T0);  // fp32-rounded (ref pc)
    const float qy = (float)(R3*X + R4*Y + R5*Z + T1);
    const float qz = (float)(R6*X + R7*Y + R8*Z + T2);
    axv[j] = -2.f*qx; ayv[j] = -2.f*qy; azv[j] = -2.f*qz;
    best[j] = __builtin_inff(); bidx[j] = 0;
    if (lane == 0) qlds[(w << 2) + j] = make_float4(qx, qy, qz, 0.f);
  }

  // ---- scan all candidates: 2 chunks of 4096, direct global->LDS ----
  for (int cb = 0; cb < NCH; ++cb) {
    const int cbase = cb << 12;
    #pragma unroll
    for (int kk = 0; kk < 8; ++kk)
      cand[(kk << 9) + tid] = p2aug[cbase + (kk << 9) + tid];
    __syncthreads();
    #pragma unroll 4
    for (int kk = 0; kk < 64; ++kk) {
      const int cidx = cbase + (kk << 6) + lane;
      float4 c = cand[(kk << 6) + lane];    // ds_read_b128, conflict-free
      #pragma unroll
      for (int j = 0; j < QPW; ++j) {
        float d = fmaf(axv[j], c.x, fmaf(ayv[j], c.y, fmaf(azv[j], c.z, c.w)));
        if (d < best[j]) { best[j] = d; bidx[j] = cidx; }
      }
    }
    __syncthreads();
  }

  // ---- wave-local FINAL argmin: packed u64 butterfly (jnp tie order) ----
  unsigned long long pk[QPW];
  #pragma unroll
  for (int j = 0; j < QPW; ++j) {
    unsigned u = __float_as_uint(best[j]);
    u ^= (unsigned)((int)u >> 31) | 0x80000000u;   // monotone float->uint
    pk[j] = ((unsigned long long)u << 32) | (unsigned)bidx[j];
  }
  #pragma unroll
  for (int j = 0; j < QPW; ++j) {
    #pragma unroll
    for (int o = 1; o < 64; o <<= 1) {
      unsigned long long other = __shfl_xor(pk[j], o, 64);
      pk[j] = (other < pk[j]) ? other : pk[j];
    }
  }
  if (lane == 0) {
    #pragma unroll
    for (int j = 0; j < QPW; ++j) pkbuf[w][j] = pk[j];
  }
  __syncthreads();

  // ---- pair sums: tid<32 handles one query (LDS-indexed, static) ----
  if (tid < 32) {
    const unsigned long long m = pkbuf[tid >> 2][tid & 3];
    const unsigned idx = (unsigned)(m & 0xffffffffull);
    const float4 q4 = qlds[tid];
    const float4 b4 = p2aug[idx];           // L2-resident gather
    const double ax = q4.x, ay = q4.y, az = q4.z;
    const double bx = b4.x, by = b4.y, bz = b4.z;
    const double d2 = (ax*ax + ay*ay + az*az) + (bx*bx + by*by + bz*bz)
                    - 2.0*(ax*bx + ay*by + az*bz);
    pairbuf[tid][0]  = sqrt(fmax(d2, 1e-12));
    pairbuf[tid][1]  = ax;    pairbuf[tid][2]  = ay;    pairbuf[tid][3]  = az;
    pairbuf[tid][4]  = bx;    pairbuf[tid][5]  = by;    pairbuf[tid][6]  = bz;
    pairbuf[tid][7]  = ax*bx; pairbuf[tid][8]  = ax*by; pairbuf[tid][9]  = ax*bz;
    pairbuf[tid][10] = ay*bx; pairbuf[tid][11] = ay*by; pairbuf[tid][12] = ay*bz;
    pairbuf[tid][13] = az*bx; pairbuf[tid][14] = az*by; pairbuf[tid][15] = az*bz;
  }
  __syncthreads();

  // ---- 16 col sums -> atomicAdd into set (bid&15): <=16-way contention ----
  if (tid < 16) {
    double ssum = 0.0;
    #pragma unroll
    for (int i = 0; i < 32; ++i) ssum += pairbuf[i][tid];
    atomicAdd(acc + ((bid & 15) << 4) + tid, ssum);
  }
  // ticket tree (wave 0 issued the adds; vmcnt orders adds before tickets)
  if (tid == 0) {
    asm volatile("s_waitcnt vmcnt(0)" ::: "memory");
    const int gi = bid & 15;
    unsigned og = atomicAdd(gtick + (gi << 4), 1u);     // 16-way
    if (og == 15u) {                                    // last of group
      unsigned orr = atomicAdd(root, 1u);               // 16-way
      if (orr == 15u) solverFlag = 1;                   // last overall
    }
  }
  __syncthreads();
  if (!solverFlag) return;

  // ================= solver path (root-last block only) =================
  double val = 0.0;
  if (tid < 256) val = atomicAdd(acc + tid, 0.0);   // RMW-read 32 lines
  if (tid < 256) setbuf[tid >> 4][tid & 15] = val;
  __syncthreads();
  if (tid < 16) {
    double t2 = 0.0;
    #pragma unroll
    for (int i = 0; i < 16; ++i) t2 += setbuf[i][tid];
    totbuf[tid] = t2;
  }
  __syncthreads();

  if (tid == 0) {
    double sm[16];
    #pragma unroll
    for (int i = 0; i < 16; ++i) sm[i] = totbuf[i];
    double R[9], T[3];
    kabsch_solve(sm, R, T);
    // compose: pc_new = R*(Rc*p1 + tc) + T = (R*Rc)*p1 + (R*tc + T)
    double Rc[9] = {R0,R1,R2,R3,R4,R5,R6,R7,R8};
    double tc[3] = {T0,T1,T2};
    double Rn[9], tn[3];
    #pragma unroll
    for (int i = 0; i < 3; ++i) {
      #pragma unroll
      for (int j = 0; j < 3; ++j)
        Rn[3*i+j] = R[3*i+0]*Rc[0+j] + R[3*i+1]*Rc[3+j] + R[3*i+2]*Rc[6+j];
      tn[i] = R[3*i+0]*tc[0] + R[3*i+1]*tc[1] + R[3*i+2]*tc[2] + T[i];
    }
    #pragma unroll
    for (int i = 0; i < 9; ++i) ctl->Rc[i] = Rn[i];
    #pragma unroll
    for (int i = 0; i < 3; ++i) ctl->tc[i] = tn[i];
    const double errnew = sm[0];            // B == 1
    ctl->done = (fabs(ctl->err - errnew) < ICP_TOL) ? 1 : 0;
    ctl->err  = errnew;
    // out = [Rc | tc] 3x4 (kabsch(p1, Rc*p1+tc) == (Rc,tc) exactly).
    #pragma unroll
    for (int i = 0; i < 3; ++i) {
      out[4*i + 0] = (float)Rn[3*i + 0];
      out[4*i + 1] = (float)Rn[3*i + 1];
      out[4*i + 2] = (float)Rn[3*i + 2];
      out[4*i + 3] = (float)tn[i];
    }
    *root = 0u;                             // reset root ticket
  }
  // reset acc + group tickets (plain stores; boundary release publishes)
  if (tid < 256) acc[tid] = 0.0;
  if (tid < 16) gtick[tid << 4] = 0u;
}

// ---------------------------------------------------------------------------
extern "C" void kernel_launch(void* const* d_in, const int* in_sizes, int n_in,
                              void* d_out, int out_size, void* d_ws, size_t ws_size,
                              hipStream_t stream) {
  const float* p1 = (const float*)d_in[0];
  const float* p2 = (const float*)d_in[1];
  float* out = (float*)d_out;

  char* ws = (char*)d_ws;
  float4* p2aug  = (float4*)ws;                        // 128 KiB
  IcpCtl* ctl    = (IcpCtl*)(ws + 128*1024);           // ~112 B
  double* acc    = (double*)(ws + 132*1024);           // 2 KiB (16 sets x 16)
  unsigned* gtick = (unsigned*)(ws + 136*1024);        // 16 tickets, 64B apart
  unsigned* root  = (unsigned*)(ws + 140*1024);        // 1 line

  icp_prep<<<N_PTS/256, 256, 0, stream>>>(p2, p2aug, ctl, acc, gtick, root);
  for (int it = 0; it < ICP_STEPS; ++it)
    icp_step<<<NBLK, BSIZE, 0, stream>>>(p1, p2aug, ctl, acc, gtick, root, out);
}